// Round 4
// baseline (47369.223 us; speedup 1.0000x reference)
//
#include <hip/hip_runtime.h>
#include <hip/hip_bf16.h>

#define B_  64
#define T_  12
#define N_  325
#define DIN 2
#define H_  128
#define BN  (B_*N_)   // 20800

typedef __hip_bfloat16 bf16;

__device__ __forceinline__ float b2f(bf16 v){ return __bfloat162float(v); }

// ---------------------------------------------------------------------------
// Dtype sniffer: supports rows sum to 1.0. flag=1 -> bf16 inputs, 0 -> fp32.
// NaN-safe (NaN comparisons false -> picks the other).
// ---------------------------------------------------------------------------
__global__ void sniff(const void* __restrict__ sup, int* __restrict__ flag){
    if (threadIdx.x == 0 && blockIdx.x == 0){
        float sb = 0.f, sf = 0.f;
        for (int n = 0; n < N_; ++n){
            sb += b2f(((const bf16*)sup)[n]);
            sf += ((const float*)sup)[n];
        }
        float db = fabsf(sb - 1.f), df = fabsf(sf - 1.f);
        *flag = (db < df) ? 1 : 0;
    }
}

__global__ void cvt(const void* __restrict__ src, float* __restrict__ dst, int n,
                    const int* __restrict__ flag){
    int i = blockIdx.x*256 + threadIdx.x;
    if (i >= n) return;
    if (*flag) dst[i] = b2f(((const bf16*)src)[i]);
    else       dst[i] = ((const float*)src)[i];
}

// ---------------------------------------------------------------------------
// msq[0]=S0, msq[1]=S0@S0, msq[2]=S1, msq[3]=S1@S1   (fp32)
// ---------------------------------------------------------------------------
__global__ void support_prep(const float* __restrict__ sup, float* __restrict__ msq){
    int s = blockIdx.z;
    int m = blockIdx.y*16 + threadIdx.y;
    int n = blockIdx.x*16 + threadIdx.x;
    __shared__ float As[16][17], Bs[16][17];
    const float* S = sup + (size_t)s*N_*N_;
    float acc = 0.f;
    for (int j0 = 0; j0 < N_; j0 += 16){
        As[threadIdx.y][threadIdx.x] = (m < N_ && j0+threadIdx.x < N_) ? S[m*N_ + j0+threadIdx.x] : 0.f;
        Bs[threadIdx.y][threadIdx.x] = (j0+threadIdx.y < N_ && n < N_) ? S[(j0+threadIdx.y)*N_ + n] : 0.f;
        __syncthreads();
        #pragma unroll
        for (int jj=0; jj<16; ++jj) acc += As[threadIdx.y][jj]*Bs[jj][threadIdx.x];
        __syncthreads();
    }
    if (m < N_ && n < N_){
        msq[(size_t)(2*s  )*N_*N_ + m*N_ + n] = S[m*N_ + n];
        msq[(size_t)(2*s+1)*N_*N_ + m*N_ + n] = acc;
    }
}

// ---------------------------------------------------------------------------
// F[local bn, 0:C] = [ x | h ] for batches [b0, b0+Bc)
// ---------------------------------------------------------------------------
__global__ void fill_xh(float* __restrict__ F, int C, int KC, int Din, int b0, int Bc,
                        const float* __restrict__ x, long xbstride,
                        const float* __restrict__ h){
    int idx = blockIdx.x*256 + threadIdx.x;
    int total = Bc*N_*C;
    if (idx >= total) return;
    int c   = idx % C;
    int bnl = idx / C;
    int n   = bnl % N_;
    int bg  = b0 + bnl / N_;
    float v;
    if (c < Din) v = x[(size_t)bg*xbstride + (size_t)n*Din + c];
    else         v = h[((size_t)bg*N_ + n)*H_ + (c - Din)];
    F[(size_t)bnl*KC + c] = v;
}

// ---------------------------------------------------------------------------
// F[local bn, Din+j] = r * h (x-part kept). zr is chunk-local, h is global.
// ---------------------------------------------------------------------------
__global__ void fill_rh(float* __restrict__ F, int KC, int Din, int b0, int Bc,
                        const float* __restrict__ zr, const float* __restrict__ h){
    int idx = blockIdx.x*256 + threadIdx.x;
    int total = Bc*N_*H_;
    if (idx >= total) return;
    int j   = idx & 127;
    int bnl = idx >> 7;
    float r  = zr[(size_t)bnl*256 + 128 + j];
    float hv = h[((size_t)b0*N_ + bnl)*128 + j];
    F[(size_t)bnl*KC + Din + j] = r * hv;
}

// ---------------------------------------------------------------------------
// Diffusion: for z=(bl,k): F[bl,:, (k+1)C:(k+2)C] = msq[k] @ F[bl,:,0:C]
// ---------------------------------------------------------------------------
template<int NJ>
__global__ __launch_bounds__(256) void diffuse(float* __restrict__ F,
                                               const float* __restrict__ msq,
                                               int C, int KC){
    int zi = blockIdx.z;
    int k  = zi & 3, bl = zi >> 2;
    const float* A  = msq + (size_t)k*N_*N_;
    const float* Bm = F + (size_t)bl*N_*KC;
    float*       Cm = F + (size_t)bl*N_*KC + (k+1)*C;
    int m0 = blockIdx.y * 64;
    int c0 = blockIdx.x * (16*NJ);
    int tid = threadIdx.x;
    int tx = tid & 15, ty = tid >> 4;
    __shared__ float As[16][68];
    __shared__ float Bs[16][16*NJ];
    float acc[4][NJ];
    #pragma unroll
    for (int i=0;i<4;++i)
        #pragma unroll
        for (int j=0;j<NJ;++j) acc[i][j]=0.f;

    for (int k0 = 0; k0 < N_; k0 += 16){
        #pragma unroll
        for (int i=0;i<4;++i){
            int m_l = (tid >> 4) + 16*i;
            int kk  = tid & 15;
            int gm = m0 + m_l, gk = k0 + kk;
            As[kk][m_l] = (gm < N_ && gk < N_) ? A[(size_t)gm*N_ + gk] : 0.f;
        }
        #pragma unroll
        for (int i=0;i<NJ;++i){
            int lin = tid + 256*i;
            int c_l = lin % (16*NJ);
            int kr  = lin / (16*NJ);
            int gn = k0 + kr, gc = c0 + c_l;
            Bs[kr][c_l] = (gn < N_ && gc < C) ? Bm[(size_t)gn*KC + gc] : 0.f;
        }
        __syncthreads();
        #pragma unroll
        for (int kk=0;kk<16;++kk){
            float4 a4 = *(const float4*)&As[kk][ty*4];
            float av[4] = {a4.x, a4.y, a4.z, a4.w};
            #pragma unroll
            for (int j=0;j<NJ;++j){
                float bv = Bs[kk][tx + 16*j];
                #pragma unroll
                for (int i=0;i<4;++i) acc[i][j] += av[i]*bv;
            }
        }
        __syncthreads();
    }
    #pragma unroll
    for (int i=0;i<4;++i){
        int m = m0 + ty*4 + i;
        if (m < N_){
            #pragma unroll
            for (int j=0;j<NJ;++j){
                int c = c0 + tx + 16*j;
                if (c < C) Cm[(size_t)m*KC + c] = acc[i][j];
            }
        }
    }
}

// ---------------------------------------------------------------------------
// GEMM over chunk rows: out = F(rows x KC) @ W(KC x Nout) + bias, fused act.
// MODE 0: zr = sigmoid(out)  (Nout=256).  MODE 1: h = z*h + (1-z)*tanh(out).
// zr chunk-local; hb = h + b0*N*128 (chunk base).
// ---------------------------------------------------------------------------
template<int MODE>
__global__ __launch_bounds__(256) void gemm_act(const float* __restrict__ F, int KC,
                                                int rows,
                                                const float* __restrict__ W,
                                                const float* __restrict__ bias,
                                                int Nout,
                                                float* __restrict__ zr,
                                                float* __restrict__ hb){
    int r0 = blockIdx.y * 64;
    int c0 = blockIdx.x * 64;
    int tid = threadIdx.x;
    int tx = tid & 15, ty = tid >> 4;
    __shared__ float As[16][68];
    __shared__ float Bs[16][64];
    float acc[4][4];
    #pragma unroll
    for (int i=0;i<4;++i)
        #pragma unroll
        for (int j=0;j<4;++j) acc[i][j]=0.f;

    for (int k0 = 0; k0 < KC; k0 += 16){
        #pragma unroll
        for (int i=0;i<4;++i){
            int m_l = (tid >> 4) + 16*i;
            int kk  = tid & 15;
            int gk  = k0 + kk;
            As[kk][m_l] = (r0+m_l < rows && gk < KC) ? F[(size_t)(r0+m_l)*KC + gk] : 0.f;
        }
        #pragma unroll
        for (int i=0;i<4;++i){
            int c_l = tid & 63;
            int kr  = (tid >> 6) + 4*i;
            int gk  = k0 + kr;
            Bs[kr][c_l] = (gk < KC) ? W[(size_t)gk*Nout + c0 + c_l] : 0.f;
        }
        __syncthreads();
        #pragma unroll
        for (int kk=0;kk<16;++kk){
            float4 a4 = *(const float4*)&As[kk][ty*4];
            float av[4] = {a4.x, a4.y, a4.z, a4.w};
            #pragma unroll
            for (int j=0;j<4;++j){
                float bv = Bs[kk][tx + 16*j];
                #pragma unroll
                for (int i=0;i<4;++i) acc[i][j] += av[i]*bv;
            }
        }
        __syncthreads();
    }
    #pragma unroll
    for (int i=0;i<4;++i){
        int r = r0 + ty*4 + i;
        if (r >= rows) continue;
        #pragma unroll
        for (int j=0;j<4;++j){
            int c = c0 + tx + 16*j;
            float v = acc[i][j] + bias[c];
            if (MODE == 0){
                v = 1.f/(1.f + __expf(-v));
                zr[(size_t)r*256 + c] = v;
            } else {
                float hc   = tanhf(v);
                float z    = zr[(size_t)r*256 + c];
                float hold = hb[(size_t)r*128 + c];
                hb[(size_t)r*128 + c] = z*hold + (1.f - z)*hc;
            }
        }
    }
}

// ---------------------------------------------------------------------------
// Projection: out = h1 @ Wp + bp ; writes fp32 xdec + fp32 d_out
// ---------------------------------------------------------------------------
__global__ __launch_bounds__(256) void proj(const float* __restrict__ h1,
                                            const float* __restrict__ Wp,
                                            const float* __restrict__ bp,
                                            float* __restrict__ xdec,
                                            float* __restrict__ out, int t){
    int row  = blockIdx.x * 4 + (threadIdx.x >> 6);
    int lane = threadIdx.x & 63;
    float v0 = h1[(size_t)row*128 + lane];
    float v1 = h1[(size_t)row*128 + 64 + lane];
    float w00 = Wp[lane*2+0],      w01 = Wp[lane*2+1];
    float w10 = Wp[(64+lane)*2+0], w11 = Wp[(64+lane)*2+1];
    float a0 = v0*w00 + v1*w10;
    float a1 = v0*w01 + v1*w11;
    #pragma unroll
    for (int off=32; off>0; off>>=1){
        a0 += __shfl_down(a0, off);
        a1 += __shfl_down(a1, off);
    }
    if (lane == 0){
        a0 += bp[0];
        a1 += bp[1];
        xdec[(size_t)row*2+0] = a0;
        xdec[(size_t)row*2+1] = a1;
        int b = row / N_, n = row % N_;
        size_t o = ((size_t)(b*T_ + t)*N_ + n)*2;
        out[o]   = a0;
        out[o+1] = a1;
    }
}

// ---------------------------------------------------------------------------
extern "C" void kernel_launch(void* const* d_in, const int* in_sizes, int n_in,
                              void* d_out, int out_size, void* d_ws, size_t ws_size,
                              hipStream_t stream){
    float* out = (float*)d_out;

    int*   flag = (int*)d_ws;
    float* p    = (float*)d_ws + 16;

    // ---- convert float inputs to fp32 scratch (skip targets, idx 1) ----
    float* cw[21];
    sniff<<<1, 64, 0, stream>>>(d_in[2], flag);
    const int idxs[20] = {0,2,3,4,5,6,7,8,9,10,11,12,13,14,15,16,17,18,19,20};
    for (int ii = 0; ii < 20; ++ii){
        int i = idxs[ii];
        int n = in_sizes[i];
        cw[i] = p;
        p += n;
        cvt<<<dim3((n+255)/256), 256, 0, stream>>>(d_in[i], cw[i], n, flag);
    }
    const float* src = cw[0];

    // ---- fixed-region layout ----
    float* msq  = p;                        p += (size_t)4*N_*N_;
    float* h0   = p;                        p += (size_t)BN*H_;
    float* h1   = p;                        p += (size_t)BN*H_;
    float* xdec = p;                        p += (size_t)BN*DIN;

    // ---- adaptive chunk size: F (Bc*N*1280) + zr (Bc*N*256) must fit ----
    size_t fixed_floats = (size_t)(p - (float*)d_ws);
    int Bc = 64;
    while (Bc > 1 &&
           (fixed_floats + (size_t)Bc*N_*1536) * sizeof(float) > ws_size) Bc >>= 1;
    float* F  = p;
    float* zr = F + (size_t)Bc*N_*1280;

    {   // supports + squared supports
        dim3 g((N_+15)/16, (N_+15)/16, 2), b(16,16);
        support_prep<<<g, b, 0, stream>>>(cw[2], msq);
    }
    hipMemsetAsync(h0, 0, sizeof(float)*(size_t)BN*H_*2, stream);  // h0 and h1

    auto cell = [&](int layer, const float* x, long xbs, float* h,
                    const float* Wg, const float* bg, const float* Wc, const float* bc){
        int C   = layer ? 256 : 130;
        int KC  = 5*C;
        int Din = layer ? 128 : 2;
        for (int b0 = 0; b0 < B_; b0 += Bc){
            int rows  = Bc*N_;
            int total = rows*C;
            int gy    = (rows + 63)/64;
            float* hb = h + (size_t)b0*N_*H_;
            fill_xh<<<dim3((total+255)/256), 256, 0, stream>>>(F, C, KC, Din, b0, Bc, x, xbs, h);
            if (layer) diffuse<4><<<dim3(4,6,4*Bc), 256, 0, stream>>>(F, msq, C, KC);
            else       diffuse<3><<<dim3(3,6,4*Bc), 256, 0, stream>>>(F, msq, C, KC);
            gemm_act<0><<<dim3(4,gy), 256, 0, stream>>>(F, KC, rows, Wg, bg, 256, zr, (float*)nullptr);
            fill_rh<<<dim3((rows*H_+255)/256), 256, 0, stream>>>(F, KC, Din, b0, Bc, zr, h);
            if (layer) diffuse<4><<<dim3(4,6,4*Bc), 256, 0, stream>>>(F, msq, C, KC);
            else       diffuse<3><<<dim3(3,6,4*Bc), 256, 0, stream>>>(F, msq, C, KC);
            gemm_act<1><<<dim3(2,gy), 256, 0, stream>>>(F, KC, rows, Wc, bc, 128, zr, hb);
        }
    };

    // ---------------- encoder ----------------
    for (int t = 0; t < T_; ++t){
        cell(0, src + (size_t)t*N_*DIN, (long)T_*N_*DIN, h0, cw[3], cw[4], cw[5], cw[6]);
        cell(1, h0, (long)N_*H_, h1, cw[7], cw[8], cw[9], cw[10]);
    }

    // ---------------- decoder ----------------
    hipMemsetAsync(xdec, 0, sizeof(float)*(size_t)BN*DIN, stream);
    for (int t = 0; t < T_; ++t){
        cell(0, xdec, (long)N_*DIN, h0, cw[11], cw[12], cw[13], cw[14]);
        cell(1, h0, (long)N_*H_, h1, cw[15], cw[16], cw[17], cw[18]);
        proj<<<dim3(BN/4), 256, 0, stream>>>(h1, cw[19], cw[20], xdec, out, t);
    }
}

// Round 5
// 10034.753 us; speedup vs baseline: 4.7205x; 4.7205x over previous
//
#include <hip/hip_runtime.h>
#include <hip/hip_bf16.h>

#define B_  64
#define T_  12
#define N_  325
#define DIN 2
#define H_  128
#define BN  (B_*N_)    // 20800
#define DPITCH 384     // bf16 supports row pitch (zero-padded past 325)

typedef __hip_bfloat16 bf16;
typedef __attribute__((ext_vector_type(8))) short short8;
typedef __attribute__((ext_vector_type(4))) float f32x4;

__device__ __forceinline__ float b2f(bf16 v){ return __bfloat162float(v); }
__device__ __forceinline__ unsigned short f2b(float f){
    __hip_bfloat16 h = __float2bfloat16(f);
    return *reinterpret_cast<unsigned short*>(&h);
}

// ---------------------------------------------------------------------------
// Dtype sniffer + fp32 conversion (inputs verified fp32, kept for robustness)
// ---------------------------------------------------------------------------
__global__ void sniff(const void* __restrict__ sup, int* __restrict__ flag){
    if (threadIdx.x == 0 && blockIdx.x == 0){
        float sb = 0.f, sf = 0.f;
        for (int n = 0; n < N_; ++n){
            sb += b2f(((const bf16*)sup)[n]);
            sf += ((const float*)sup)[n];
        }
        float db = fabsf(sb - 1.f), df = fabsf(sf - 1.f);
        *flag = (db < df) ? 1 : 0;
    }
}

__global__ void cvt(const void* __restrict__ src, float* __restrict__ dst, int n,
                    const int* __restrict__ flag){
    int i = blockIdx.x*256 + threadIdx.x;
    if (i >= n) return;
    if (*flag) dst[i] = b2f(((const bf16*)src)[i]);
    else       dst[i] = ((const float*)src)[i];
}

__global__ void cvt_b16(const float* __restrict__ src, unsigned short* __restrict__ dst, int n){
    int i = blockIdx.x*256 + threadIdx.x;
    if (i < n) dst[i] = f2b(src[i]);
}

// ---------------------------------------------------------------------------
// msq[0]=S0, msq[1]=S0@S0, msq[2]=S1, msq[3]=S1@S1   (fp32)
// ---------------------------------------------------------------------------
__global__ void support_prep(const float* __restrict__ sup, float* __restrict__ msq){
    int s = blockIdx.z;
    int m = blockIdx.y*16 + threadIdx.y;
    int n = blockIdx.x*16 + threadIdx.x;
    __shared__ float As[16][17], Bs[16][17];
    const float* S = sup + (size_t)s*N_*N_;
    float acc = 0.f;
    for (int j0 = 0; j0 < N_; j0 += 16){
        As[threadIdx.y][threadIdx.x] = (m < N_ && j0+threadIdx.x < N_) ? S[m*N_ + j0+threadIdx.x] : 0.f;
        Bs[threadIdx.y][threadIdx.x] = (j0+threadIdx.y < N_ && n < N_) ? S[(j0+threadIdx.y)*N_ + n] : 0.f;
        __syncthreads();
        #pragma unroll
        for (int jj=0; jj<16; ++jj) acc += As[threadIdx.y][jj]*Bs[jj][threadIdx.x];
        __syncthreads();
    }
    if (m < N_ && n < N_){
        msq[(size_t)(2*s  )*N_*N_ + m*N_ + n] = S[m*N_ + n];
        msq[(size_t)(2*s+1)*N_*N_ + m*N_ + n] = acc;
    }
}

// asq[k][m][col] = bf16(msq[k][m][col]) with zero pad to DPITCH
__global__ void asq_prep(const float* __restrict__ msq, unsigned short* __restrict__ asq){
    int idx = blockIdx.x*256 + threadIdx.x;
    int total = 4*N_*DPITCH;
    if (idx >= total) return;
    int col = idx % DPITCH;
    int rm  = idx / DPITCH;
    int m   = rm % N_;
    int k   = rm / N_;
    asq[idx] = (col < N_) ? f2b(msq[((size_t)k*N_ + m)*N_ + col]) : 0;
}

// ---------------------------------------------------------------------------
// F[local bn, 0:C] = [ x | h ]  (bf16)
// ---------------------------------------------------------------------------
__global__ void fill_xh(unsigned short* __restrict__ F, int C, int KC, int Din, int b0, int Bc,
                        const float* __restrict__ x, long xbstride,
                        const float* __restrict__ h){
    int idx = blockIdx.x*256 + threadIdx.x;
    int total = Bc*N_*C;
    if (idx >= total) return;
    int c   = idx % C;
    int bnl = idx / C;
    int n   = bnl % N_;
    int bg  = b0 + bnl / N_;
    float v;
    if (c < Din) v = x[(size_t)bg*xbstride + (size_t)n*Din + c];
    else         v = h[((size_t)bg*N_ + n)*H_ + (c - Din)];
    F[(size_t)bnl*KC + c] = f2b(v);
}

// F[local bn, Din+j] = bf16(r * h)
__global__ void fill_rh(unsigned short* __restrict__ F, int KC, int Din, int b0, int Bc,
                        const float* __restrict__ zr, const float* __restrict__ h){
    int idx = blockIdx.x*256 + threadIdx.x;
    int total = Bc*N_*H_;
    if (idx >= total) return;
    int j   = idx & 127;
    int bnl = idx >> 7;
    float r  = zr[(size_t)bnl*256 + 128 + j];
    float hv = h[((size_t)b0*N_ + bnl)*128 + j];
    F[(size_t)bnl*KC + Din + j] = f2b(r * hv);
}

// ---------------------------------------------------------------------------
// MFMA diffusion: for z=(bl,k): F[bl,:, (k+1)C:(k+2)C] = Sk(325x325) @ F[bl,:,0:C]
// Block tile 128(m) x 64(c), BK=64, 4 waves: wave w -> rows [w*32, w*32+32).
// ---------------------------------------------------------------------------
__global__ __launch_bounds__(256) void diffuse_mfma(unsigned short* __restrict__ F,
                                                    const unsigned short* __restrict__ asq,
                                                    int C, int KC){
    int zi = blockIdx.z;
    int k  = zi & 3, bl = zi >> 2;
    const unsigned short* A  = asq + (size_t)k*N_*DPITCH;
    const unsigned short* Bm = F + (size_t)bl*N_*KC;
    unsigned short*       Cm = F + (size_t)bl*N_*KC + (size_t)(k+1)*C;

    int m0 = blockIdx.y * 128;
    int c0 = blockIdx.x * 64;
    int tid = threadIdx.x;
    int wv = tid >> 6, lane = tid & 63, l15 = lane & 15, quad = lane >> 4;

    __shared__ unsigned short As[128][72];
    __shared__ unsigned short Bt[64][72];

    f32x4 acc[2][4];
    #pragma unroll
    for (int i=0;i<2;++i)
        #pragma unroll
        for (int j=0;j<4;++j) acc[i][j] = (f32x4){0.f,0.f,0.f,0.f};

    for (int k0 = 0; k0 < N_; k0 += 64){
        // ---- stage A tile: 128 rows x 64 k (asq zero-padded in k) ----
        #pragma unroll
        for (int it=0; it<4; ++it){
            int lin = it*256 + tid;
            int row = lin >> 3, seg = lin & 7;
            int gm = m0 + row;
            uint4 v = {0u,0u,0u,0u};
            if (gm < N_) v = *(const uint4*)(A + (size_t)gm*DPITCH + k0 + seg*8);
            *(uint4*)&As[row][seg*8] = v;
        }
        // ---- stage B tile transposed: Bt[c][k] = F[node k][chan c] ----
        {
            int kr = tid & 63, cs = tid >> 6;
            int gk = k0 + kr;
            int cbase = c0 + cs*16;
            if (gk < N_ && cbase + 15 < C){
                const unsigned* g = (const unsigned*)(Bm + (size_t)gk*KC + cbase);
                #pragma unroll
                for (int i=0;i<8;++i){
                    unsigned w = g[i];
                    Bt[cs*16 + 2*i    ][kr] = (unsigned short)(w & 0xffffu);
                    Bt[cs*16 + 2*i + 1][kr] = (unsigned short)(w >> 16);
                }
            } else {
                #pragma unroll
                for (int i=0;i<16;++i){
                    int c = cbase + i;
                    Bt[cs*16 + i][kr] = (gk < N_ && c < C) ? Bm[(size_t)gk*KC + c] : 0;
                }
            }
        }
        __syncthreads();
        #pragma unroll
        for (int ks = 0; ks < 64; ks += 32){
            short8 a0 = *(const short8*)&As[wv*32      + l15][ks + quad*8];
            short8 a1 = *(const short8*)&As[wv*32 + 16 + l15][ks + quad*8];
            short8 b0 = *(const short8*)&Bt[     l15][ks + quad*8];
            short8 b1 = *(const short8*)&Bt[16 + l15][ks + quad*8];
            short8 b2 = *(const short8*)&Bt[32 + l15][ks + quad*8];
            short8 b3 = *(const short8*)&Bt[48 + l15][ks + quad*8];
            acc[0][0] = __builtin_amdgcn_mfma_f32_16x16x32_bf16(a0,b0,acc[0][0],0,0,0);
            acc[0][1] = __builtin_amdgcn_mfma_f32_16x16x32_bf16(a0,b1,acc[0][1],0,0,0);
            acc[0][2] = __builtin_amdgcn_mfma_f32_16x16x32_bf16(a0,b2,acc[0][2],0,0,0);
            acc[0][3] = __builtin_amdgcn_mfma_f32_16x16x32_bf16(a0,b3,acc[0][3],0,0,0);
            acc[1][0] = __builtin_amdgcn_mfma_f32_16x16x32_bf16(a1,b0,acc[1][0],0,0,0);
            acc[1][1] = __builtin_amdgcn_mfma_f32_16x16x32_bf16(a1,b1,acc[1][1],0,0,0);
            acc[1][2] = __builtin_amdgcn_mfma_f32_16x16x32_bf16(a1,b2,acc[1][2],0,0,0);
            acc[1][3] = __builtin_amdgcn_mfma_f32_16x16x32_bf16(a1,b3,acc[1][3],0,0,0);
        }
        __syncthreads();
    }
    // ---- store: C/D layout col=lane&15, row=quad*4+reg ----
    #pragma unroll
    for (int i=0;i<2;++i){
        #pragma unroll
        for (int j=0;j<4;++j){
            int c = c0 + j*16 + l15;
            #pragma unroll
            for (int r=0;r<4;++r){
                int m = m0 + wv*32 + i*16 + quad*4 + r;
                if (m < N_ && c < C) Cm[(size_t)m*KC + c] = f2b(acc[i][j][r]);
            }
        }
    }
}

// ---------------------------------------------------------------------------
// MFMA GEMM + fused epilogue: out = F(rows x KC) @ W(KC x Nout) + bias
// MODE 0: zr = sigmoid(out)  (Nout=256). MODE 1: h = z*h + (1-z)*tanh(out).
// ---------------------------------------------------------------------------
template<int MODE>
__global__ __launch_bounds__(256) void gemm_mfma(const unsigned short* __restrict__ Fb, int KC,
                                                 int rows,
                                                 const unsigned short* __restrict__ W,
                                                 const float* __restrict__ bias,
                                                 int Nout,
                                                 float* __restrict__ zr,
                                                 float* __restrict__ hb){
    int r0 = blockIdx.y * 128;
    int c0 = blockIdx.x * 64;
    int tid = threadIdx.x;
    int wv = tid >> 6, lane = tid & 63, l15 = lane & 15, quad = lane >> 4;

    __shared__ unsigned short As[128][72];
    __shared__ unsigned short Wt[64][72];

    f32x4 acc[2][4];
    #pragma unroll
    for (int i=0;i<2;++i)
        #pragma unroll
        for (int j=0;j<4;++j) acc[i][j] = (f32x4){0.f,0.f,0.f,0.f};

    for (int k0 = 0; k0 < KC; k0 += 64){
        // ---- stage A (F rows, k-contiguous) ----
        #pragma unroll
        for (int it=0; it<4; ++it){
            int lin = it*256 + tid;
            int row = lin >> 3, seg = lin & 7;
            int gr = r0 + row, gk = k0 + seg*8;
            if (gr < rows && gk + 7 < KC){
                const unsigned* g = (const unsigned*)(Fb + (size_t)gr*KC + gk);
                uint4 v; v.x=g[0]; v.y=g[1]; v.z=g[2]; v.w=g[3];
                *(uint4*)&As[row][seg*8] = v;
            } else {
                #pragma unroll
                for (int e=0;e<8;++e)
                    As[row][seg*8+e] = (gr < rows && gk+e < KC) ? Fb[(size_t)gr*KC + gk+e] : 0;
            }
        }
        // ---- stage W transposed: Wt[c][k] ----
        {
            int kr = tid & 63, cs = tid >> 6;
            int gk = k0 + kr;
            int cbase = c0 + cs*16;
            if (gk < KC){
                const unsigned* g = (const unsigned*)(W + (size_t)gk*Nout + cbase);
                #pragma unroll
                for (int i=0;i<8;++i){
                    unsigned w = g[i];
                    Wt[cs*16 + 2*i    ][kr] = (unsigned short)(w & 0xffffu);
                    Wt[cs*16 + 2*i + 1][kr] = (unsigned short)(w >> 16);
                }
            } else {
                #pragma unroll
                for (int i=0;i<16;++i) Wt[cs*16 + i][kr] = 0;
            }
        }
        __syncthreads();
        #pragma unroll
        for (int ks = 0; ks < 64; ks += 32){
            short8 a0 = *(const short8*)&As[wv*32      + l15][ks + quad*8];
            short8 a1 = *(const short8*)&As[wv*32 + 16 + l15][ks + quad*8];
            short8 b0 = *(const short8*)&Wt[     l15][ks + quad*8];
            short8 b1 = *(const short8*)&Wt[16 + l15][ks + quad*8];
            short8 b2 = *(const short8*)&Wt[32 + l15][ks + quad*8];
            short8 b3 = *(const short8*)&Wt[48 + l15][ks + quad*8];
            acc[0][0] = __builtin_amdgcn_mfma_f32_16x16x32_bf16(a0,b0,acc[0][0],0,0,0);
            acc[0][1] = __builtin_amdgcn_mfma_f32_16x16x32_bf16(a0,b1,acc[0][1],0,0,0);
            acc[0][2] = __builtin_amdgcn_mfma_f32_16x16x32_bf16(a0,b2,acc[0][2],0,0,0);
            acc[0][3] = __builtin_amdgcn_mfma_f32_16x16x32_bf16(a0,b3,acc[0][3],0,0,0);
            acc[1][0] = __builtin_amdgcn_mfma_f32_16x16x32_bf16(a1,b0,acc[1][0],0,0,0);
            acc[1][1] = __builtin_amdgcn_mfma_f32_16x16x32_bf16(a1,b1,acc[1][1],0,0,0);
            acc[1][2] = __builtin_amdgcn_mfma_f32_16x16x32_bf16(a1,b2,acc[1][2],0,0,0);
            acc[1][3] = __builtin_amdgcn_mfma_f32_16x16x32_bf16(a1,b3,acc[1][3],0,0,0);
        }
        __syncthreads();
    }
    // ---- fused epilogue ----
    #pragma unroll
    for (int i=0;i<2;++i){
        #pragma unroll
        for (int j=0;j<4;++j){
            int c = c0 + j*16 + l15;
            #pragma unroll
            for (int r=0;r<4;++r){
                int gr = r0 + wv*32 + i*16 + quad*4 + r;
                if (gr >= rows) continue;
                float v = acc[i][j][r] + bias[c];
                if (MODE == 0){
                    v = 1.f/(1.f + __expf(-v));
                    zr[(size_t)gr*256 + c] = v;
                } else {
                    float hc   = tanhf(v);
                    float z    = zr[(size_t)gr*256 + c];
                    float hold = hb[(size_t)gr*128 + c];
                    hb[(size_t)gr*128 + c] = z*hold + (1.f - z)*hc;
                }
            }
        }
    }
}

// ---------------------------------------------------------------------------
// Projection: out = h1 @ Wp + bp ; fp32 xdec + fp32 d_out
// ---------------------------------------------------------------------------
__global__ __launch_bounds__(256) void proj(const float* __restrict__ h1,
                                            const float* __restrict__ Wp,
                                            const float* __restrict__ bp,
                                            float* __restrict__ xdec,
                                            float* __restrict__ out, int t){
    int row  = blockIdx.x * 4 + (threadIdx.x >> 6);
    int lane = threadIdx.x & 63;
    float v0 = h1[(size_t)row*128 + lane];
    float v1 = h1[(size_t)row*128 + 64 + lane];
    float w00 = Wp[lane*2+0],      w01 = Wp[lane*2+1];
    float w10 = Wp[(64+lane)*2+0], w11 = Wp[(64+lane)*2+1];
    float a0 = v0*w00 + v1*w10;
    float a1 = v0*w01 + v1*w11;
    #pragma unroll
    for (int off=32; off>0; off>>=1){
        a0 += __shfl_down(a0, off);
        a1 += __shfl_down(a1, off);
    }
    if (lane == 0){
        a0 += bp[0];
        a1 += bp[1];
        xdec[(size_t)row*2+0] = a0;
        xdec[(size_t)row*2+1] = a1;
        int b = row / N_, n = row % N_;
        size_t o = ((size_t)(b*T_ + t)*N_ + n)*2;
        out[o]   = a0;
        out[o+1] = a1;
    }
}

// ---------------------------------------------------------------------------
extern "C" void kernel_launch(void* const* d_in, const int* in_sizes, int n_in,
                              void* d_out, int out_size, void* d_ws, size_t ws_size,
                              hipStream_t stream){
    float* out = (float*)d_out;

    char* pb = (char*)d_ws;
    auto alloc = [&](size_t bytes)->void*{
        void* r = (void*)pb;
        pb += (bytes + 255) & ~(size_t)255;
        return r;
    };

    int* flag = (int*)alloc(16);
    sniff<<<1, 64, 0, stream>>>(d_in[2], flag);

    // fp32 copies of float inputs (skip targets idx 1)
    float* cw[21];
    const int idxs[20] = {0,2,3,4,5,6,7,8,9,10,11,12,13,14,15,16,17,18,19,20};
    for (int ii = 0; ii < 20; ++ii){
        int i = idxs[ii];
        int n = in_sizes[i];
        cw[i] = (float*)alloc((size_t)n*4);
        cvt<<<dim3((n+255)/256), 256, 0, stream>>>(d_in[i], cw[i], n, flag);
    }
    const float* src = cw[0];

    float* msq  = (float*)alloc((size_t)4*N_*N_*4);
    float* h0   = (float*)alloc((size_t)BN*H_*4);
    float* h1   = (float*)alloc((size_t)BN*H_*4);
    float* xdec = (float*)alloc((size_t)BN*DIN*4);
    unsigned short* asq = (unsigned short*)alloc((size_t)4*N_*DPITCH*2);

    // bf16 weights (Wg0,Wc0,Wg1,Wc1 for enc then dec): input idx 3,5,7,9,11,13,15,17
    const int widx[8] = {3,5,7,9,11,13,15,17};
    unsigned short* wb[8];
    for (int i=0;i<8;++i){
        int n = in_sizes[widx[i]];
        wb[i] = (unsigned short*)alloc((size_t)n*2);
        cvt_b16<<<dim3((n+255)/256), 256, 0, stream>>>(cw[widx[i]], wb[i], n);
    }

    // adaptive chunk: F (Bc*N*1280 bf16) + zr (Bc*N*256 f32)
    size_t fixed = (size_t)(pb - (char*)d_ws);
    int Bc = 64;
    while (Bc > 1 && fixed + 512 + (size_t)Bc*N_*(1280*2 + 256*4) > ws_size) Bc >>= 1;
    float* zr          = (float*)alloc((size_t)Bc*N_*256*4);
    unsigned short* F  = (unsigned short*)alloc((size_t)Bc*N_*1280*2);

    {   // supports + squared supports, then bf16-padded copy
        dim3 g((N_+15)/16, (N_+15)/16, 2), b(16,16);
        support_prep<<<g, b, 0, stream>>>(cw[2], msq);
        int tot = 4*N_*DPITCH;
        asq_prep<<<dim3((tot+255)/256), 256, 0, stream>>>(msq, asq);
    }
    hipMemsetAsync(h0, 0, sizeof(float)*(size_t)BN*H_*2, stream);  // h0 and h1

    auto cell = [&](int layer, const float* x, long xbs, float* h,
                    const unsigned short* Wg, const float* bg,
                    const unsigned short* Wc, const float* bc){
        int C   = layer ? 256 : 130;
        int KC  = 5*C;
        int Din = layer ? 128 : 2;
        int ctiles = (C + 63)/64;
        for (int b0 = 0; b0 < B_; b0 += Bc){
            int rows = Bc*N_;
            int gy   = (rows + 127)/128;
            float* hb = h + (size_t)b0*N_*H_;
            dim3 gd(ctiles, (N_+127)/128, 4*Bc);
            fill_xh<<<dim3((rows*C+255)/256), 256, 0, stream>>>(F, C, KC, Din, b0, Bc, x, xbs, h);
            diffuse_mfma<<<gd, 256, 0, stream>>>(F, asq, C, KC);
            gemm_mfma<0><<<dim3(4, gy), 256, 0, stream>>>(F, KC, rows, Wg, bg, 256, zr, (float*)nullptr);
            fill_rh<<<dim3((rows*H_+255)/256), 256, 0, stream>>>(F, KC, Din, b0, Bc, zr, h);
            diffuse_mfma<<<gd, 256, 0, stream>>>(F, asq, C, KC);
            gemm_mfma<1><<<dim3(2, gy), 256, 0, stream>>>(F, KC, rows, Wc, bc, 128, zr, hb);
        }
    };

    // ---------------- encoder ----------------
    for (int t = 0; t < T_; ++t){
        cell(0, src + (size_t)t*N_*DIN, (long)T_*N_*DIN, h0, wb[0], cw[4], wb[1], cw[6]);
        cell(1, h0, (long)N_*H_, h1, wb[2], cw[8], wb[3], cw[10]);
    }

    // ---------------- decoder ----------------
    hipMemsetAsync(xdec, 0, sizeof(float)*(size_t)BN*DIN, stream);
    for (int t = 0; t < T_; ++t){
        cell(0, xdec, (long)N_*DIN, h0, wb[4], cw[12], wb[5], cw[14]);
        cell(1, h0, (long)N_*H_, h1, wb[6], cw[16], wb[7], cw[18]);
        proj<<<dim3(BN/4), 256, 0, stream>>>(h1, cw[19], cw[20], xdec, out, t);
    }
}

// Round 6
// 9982.931 us; speedup vs baseline: 4.7450x; 1.0052x over previous
//
#include <hip/hip_runtime.h>
#include <hip/hip_bf16.h>

#define B_  64
#define T_  12
#define N_  325
#define DIN 2
#define H_  128
#define BN  (B_*N_)    // 20800
#define DPITCH 384     // padded node pitch for transposed/support buffers

typedef __hip_bfloat16 bf16;
typedef unsigned short u16;
typedef __attribute__((ext_vector_type(8))) short short8;
typedef __attribute__((ext_vector_type(4))) float f32x4;

__device__ __forceinline__ float b2f(bf16 v){ return __bfloat162float(v); }
__device__ __forceinline__ u16 f2b(float f){
    __hip_bfloat16 h = __float2bfloat16(f);
    return *reinterpret_cast<u16*>(&h);
}

// ---------------------------------------------------------------------------
// Dtype sniffer + fp32 conversion
// ---------------------------------------------------------------------------
__global__ void sniff(const void* __restrict__ sup, int* __restrict__ flag){
    if (threadIdx.x == 0 && blockIdx.x == 0){
        float sb = 0.f, sf = 0.f;
        for (int n = 0; n < N_; ++n){
            sb += b2f(((const bf16*)sup)[n]);
            sf += ((const float*)sup)[n];
        }
        float db = fabsf(sb - 1.f), df = fabsf(sf - 1.f);
        *flag = (db < df) ? 1 : 0;
    }
}

__global__ void cvt(const void* __restrict__ src, float* __restrict__ dst, int n,
                    const int* __restrict__ flag){
    int i = blockIdx.x*256 + threadIdx.x;
    if (i >= n) return;
    if (*flag) dst[i] = b2f(((const bf16*)src)[i]);
    else       dst[i] = ((const float*)src)[i];
}

// ---------------------------------------------------------------------------
// msq[0]=S0, msq[1]=S0@S0, msq[2]=S1, msq[3]=S1@S1   (fp32)
// ---------------------------------------------------------------------------
__global__ void support_prep(const float* __restrict__ sup, float* __restrict__ msq){
    int s = blockIdx.z;
    int m = blockIdx.y*16 + threadIdx.y;
    int n = blockIdx.x*16 + threadIdx.x;
    __shared__ float As[16][17], Bs[16][17];
    const float* S = sup + (size_t)s*N_*N_;
    float acc = 0.f;
    for (int j0 = 0; j0 < N_; j0 += 16){
        As[threadIdx.y][threadIdx.x] = (m < N_ && j0+threadIdx.x < N_) ? S[m*N_ + j0+threadIdx.x] : 0.f;
        Bs[threadIdx.y][threadIdx.x] = (j0+threadIdx.y < N_ && n < N_) ? S[(j0+threadIdx.y)*N_ + n] : 0.f;
        __syncthreads();
        #pragma unroll
        for (int jj=0; jj<16; ++jj) acc += As[threadIdx.y][jj]*Bs[jj][threadIdx.x];
        __syncthreads();
    }
    if (m < N_ && n < N_){
        msq[(size_t)(2*s  )*N_*N_ + m*N_ + n] = S[m*N_ + n];
        msq[(size_t)(2*s+1)*N_*N_ + m*N_ + n] = acc;
    }
}

// asq[k][m][col] = bf16(msq[k][m][col]) zero-padded to DPITCH cols
__global__ void asq_prep(const float* __restrict__ msq, u16* __restrict__ asq){
    int idx = blockIdx.x*256 + threadIdx.x;
    int total = 4*N_*DPITCH;
    if (idx >= total) return;
    int col = idx % DPITCH;
    int rm  = idx / DPITCH;
    int m   = rm % N_;
    int k   = rm / N_;
    asq[idx] = (col < N_) ? f2b(msq[((size_t)k*N_ + m)*N_ + col]) : 0;
}

// ---------------------------------------------------------------------------
// Weight transpose: W[KC][Nout] fp32 -> Wt[Nout][KCpad] bf16 (k zero-padded)
// grid (KCpad/64, Nout/64), 256 thr
// ---------------------------------------------------------------------------
__global__ __launch_bounds__(256) void wtrans(const float* __restrict__ W, u16* __restrict__ Wt,
                                              int KC, int Nout, int KCpad){
    int k0 = blockIdx.x*64, c0 = blockIdx.y*64;
    int tid = threadIdx.x;
    __shared__ u16 T[64][72];
    #pragma unroll
    for (int it=0; it<2; ++it){
        int lin = it*256 + tid;
        int kl = lin >> 3, seg = lin & 7;
        int gk = k0 + kl, gc = c0 + seg*8;
        u16 tmp[8];
        #pragma unroll
        for (int e=0;e<8;++e) tmp[e] = (gk < KC) ? f2b(W[(size_t)gk*Nout + gc + e]) : 0;
        *(uint4*)&T[kl][seg*8] = *(const uint4*)tmp;
    }
    __syncthreads();
    #pragma unroll
    for (int it=0; it<2; ++it){
        int lin = it*256 + tid;
        int cl = lin >> 3, seg = lin & 7;
        u16 tmp[8];
        #pragma unroll
        for (int j=0;j<8;++j) tmp[j] = T[seg*8+j][cl];
        *(uint4*)(Wt + (size_t)(c0+cl)*KCpad + k0 + seg*8) = *(const uint4*)tmp;
    }
}

// ---------------------------------------------------------------------------
// F slot0 transpose: F[bl][node][c] -> Ft[bl][c][node] (node pitch DPITCH,
// zero-padded in node and c). grid (6, Cpad/64, Bc)
// ---------------------------------------------------------------------------
__global__ __launch_bounds__(256) void ftrans(const u16* __restrict__ F, u16* __restrict__ Ft,
                                              int C, int KC, int Cpad){
    int bl = blockIdx.z;
    int n0 = blockIdx.x*64, c0 = blockIdx.y*64;
    int tid = threadIdx.x;
    const u16* Fb = F  + (size_t)bl*N_*KC;
    u16*       Fo = Ft + (size_t)bl*Cpad*DPITCH;
    __shared__ u16 T[64][72];
    #pragma unroll
    for (int it=0; it<2; ++it){
        int lin = it*256 + tid;
        int nl = lin >> 3, seg = lin & 7;
        int gn = n0 + nl, gc = c0 + seg*8;
        if (gn < N_ && gc + 7 < C){
            *(uint4*)&T[nl][seg*8] = *(const uint4*)(Fb + (size_t)gn*KC + gc);
        } else {
            u16 tmp[8];
            #pragma unroll
            for (int e=0;e<8;++e) tmp[e] = (gn < N_ && gc+e < C) ? Fb[(size_t)gn*KC + gc + e] : 0;
            *(uint4*)&T[nl][seg*8] = *(const uint4*)tmp;
        }
    }
    __syncthreads();
    #pragma unroll
    for (int it=0; it<2; ++it){
        int lin = it*256 + tid;
        int cl = lin >> 3, seg = lin & 7;
        u16 tmp[8];
        #pragma unroll
        for (int j=0;j<8;++j) tmp[j] = T[seg*8+j][cl];
        *(uint4*)(Fo + (size_t)(c0+cl)*DPITCH + n0 + seg*8) = *(const uint4*)tmp;
    }
}

// ---------------------------------------------------------------------------
// F[local bn, 0:C] = [ x | h ]  (bf16)
// ---------------------------------------------------------------------------
__global__ void fill_xh(u16* __restrict__ F, int C, int KC, int Din, int b0, int Bc,
                        const float* __restrict__ x, long xbstride,
                        const float* __restrict__ h){
    int idx = blockIdx.x*256 + threadIdx.x;
    int total = Bc*N_*C;
    if (idx >= total) return;
    int c   = idx % C;
    int bnl = idx / C;
    int n   = bnl % N_;
    int bg  = b0 + bnl / N_;
    float v;
    if (c < Din) v = x[(size_t)bg*xbstride + (size_t)n*Din + c];
    else         v = h[((size_t)bg*N_ + n)*H_ + (c - Din)];
    F[(size_t)bnl*KC + c] = f2b(v);
}

// F[local bn, Din+j] = bf16(r * h)
__global__ void fill_rh(u16* __restrict__ F, int KC, int Din, int b0, int Bc,
                        const float* __restrict__ zr, const float* __restrict__ h){
    int idx = blockIdx.x*256 + threadIdx.x;
    int total = Bc*N_*H_;
    if (idx >= total) return;
    int j   = idx & 127;
    int bnl = idx >> 7;
    float r  = zr[(size_t)bnl*256 + 128 + j];
    float hv = h[((size_t)b0*N_ + bnl)*128 + j];
    F[(size_t)bnl*KC + Din + j] = f2b(r * hv);
}

// ---------------------------------------------------------------------------
// MFMA diffusion: F[bl,:, (k+1)C:(k+2)C] = Sk @ slot0, B from Ft (pre-transposed)
// Block 128(m) x 64(c), BK=64, 4 waves.
// ---------------------------------------------------------------------------
__global__ __launch_bounds__(256) void diffuse_mfma(u16* __restrict__ F,
                                                    const u16* __restrict__ Ft,
                                                    const u16* __restrict__ asq,
                                                    int C, int KC, int Cpad){
    int zi = blockIdx.z;
    int k  = zi & 3, bl = zi >> 2;
    const u16* A  = asq + (size_t)k*N_*DPITCH;
    const u16* Bt_g = Ft + (size_t)bl*Cpad*DPITCH;
    u16*       Cm = F + (size_t)bl*N_*KC + (size_t)(k+1)*C;

    int m0 = blockIdx.y * 128;
    int c0 = blockIdx.x * 64;
    int tid = threadIdx.x;
    int wv = tid >> 6, lane = tid & 63, l15 = lane & 15, quad = lane >> 4;

    __shared__ u16 As[128][72];
    __shared__ u16 Bt[64][72];

    f32x4 acc[2][4];
    #pragma unroll
    for (int i=0;i<2;++i)
        #pragma unroll
        for (int j=0;j<4;++j) acc[i][j] = (f32x4){0.f,0.f,0.f,0.f};

    for (int k0 = 0; k0 < N_; k0 += 64){
        // A tile: 128 m-rows x 64 k (asq zero-padded in k)
        #pragma unroll
        for (int it=0; it<4; ++it){
            int lin = it*256 + tid;
            int row = lin >> 3, seg = lin & 7;
            int gm = m0 + row;
            uint4 v = {0u,0u,0u,0u};
            if (gm < N_) v = *(const uint4*)(A + (size_t)gm*DPITCH + k0 + seg*8);
            *(uint4*)&As[row][seg*8] = v;
        }
        // B tile: 64 c-rows x 64 k straight from Ft (already transposed+padded)
        #pragma unroll
        for (int it=0; it<2; ++it){
            int lin = it*256 + tid;
            int row = lin >> 3, seg = lin & 7;
            *(uint4*)&Bt[row][seg*8] =
                *(const uint4*)(Bt_g + (size_t)(c0+row)*DPITCH + k0 + seg*8);
        }
        __syncthreads();
        #pragma unroll
        for (int ks = 0; ks < 64; ks += 32){
            short8 a0 = *(const short8*)&As[wv*32      + l15][ks + quad*8];
            short8 a1 = *(const short8*)&As[wv*32 + 16 + l15][ks + quad*8];
            short8 b0 = *(const short8*)&Bt[     l15][ks + quad*8];
            short8 b1 = *(const short8*)&Bt[16 + l15][ks + quad*8];
            short8 b2 = *(const short8*)&Bt[32 + l15][ks + quad*8];
            short8 b3 = *(const short8*)&Bt[48 + l15][ks + quad*8];
            acc[0][0] = __builtin_amdgcn_mfma_f32_16x16x32_bf16(a0,b0,acc[0][0],0,0,0);
            acc[0][1] = __builtin_amdgcn_mfma_f32_16x16x32_bf16(a0,b1,acc[0][1],0,0,0);
            acc[0][2] = __builtin_amdgcn_mfma_f32_16x16x32_bf16(a0,b2,acc[0][2],0,0,0);
            acc[0][3] = __builtin_amdgcn_mfma_f32_16x16x32_bf16(a0,b3,acc[0][3],0,0,0);
            acc[1][0] = __builtin_amdgcn_mfma_f32_16x16x32_bf16(a1,b0,acc[1][0],0,0,0);
            acc[1][1] = __builtin_amdgcn_mfma_f32_16x16x32_bf16(a1,b1,acc[1][1],0,0,0);
            acc[1][2] = __builtin_amdgcn_mfma_f32_16x16x32_bf16(a1,b2,acc[1][2],0,0,0);
            acc[1][3] = __builtin_amdgcn_mfma_f32_16x16x32_bf16(a1,b3,acc[1][3],0,0,0);
        }
        __syncthreads();
    }
    #pragma unroll
    for (int i=0;i<2;++i){
        #pragma unroll
        for (int j=0;j<4;++j){
            int c = c0 + j*16 + l15;
            #pragma unroll
            for (int r=0;r<4;++r){
                int m = m0 + wv*32 + i*16 + quad*4 + r;
                if (m < N_ && c < C) Cm[(size_t)m*KC + c] = f2b(acc[i][j][r]);
            }
        }
    }
}

// ---------------------------------------------------------------------------
// MFMA GEMM + fused epilogue: out = F(rows x KC) @ W + bias. B from Wt.
// MODE 0: zr = sigmoid(out) (Nout=256). MODE 1: h = z*h + (1-z)*tanh(out).
// ---------------------------------------------------------------------------
template<int MODE>
__global__ __launch_bounds__(256) void gemm_mfma(const u16* __restrict__ Fb, int KC,
                                                 int rows,
                                                 const u16* __restrict__ Wt, int KCpad,
                                                 const float* __restrict__ bias,
                                                 int Nout,
                                                 float* __restrict__ zr,
                                                 float* __restrict__ hb){
    int r0 = blockIdx.y * 128;
    int c0 = blockIdx.x * 64;
    int tid = threadIdx.x;
    int wv = tid >> 6, lane = tid & 63, l15 = lane & 15, quad = lane >> 4;

    __shared__ u16 As[128][72];
    __shared__ u16 Bs[64][72];

    f32x4 acc[2][4];
    #pragma unroll
    for (int i=0;i<2;++i)
        #pragma unroll
        for (int j=0;j<4;++j) acc[i][j] = (f32x4){0.f,0.f,0.f,0.f};

    for (int k0 = 0; k0 < KCpad; k0 += 64){
        // A: F rows, k-contiguous (guard rows and KC tail)
        #pragma unroll
        for (int it=0; it<4; ++it){
            int lin = it*256 + tid;
            int row = lin >> 3, seg = lin & 7;
            int gr = r0 + row, gk = k0 + seg*8;
            if (gr < rows && gk + 7 < KC){
                *(uint4*)&As[row][seg*8] = *(const uint4*)(Fb + (size_t)gr*KC + gk);
            } else {
                u16 tmp[8];
                #pragma unroll
                for (int e=0;e<8;++e)
                    tmp[e] = (gr < rows && gk+e < KC) ? Fb[(size_t)gr*KC + gk+e] : 0;
                *(uint4*)&As[row][seg*8] = *(const uint4*)tmp;
            }
        }
        // B: straight uint4 from pre-transposed Wt (zero-padded in k)
        #pragma unroll
        for (int it=0; it<2; ++it){
            int lin = it*256 + tid;
            int row = lin >> 3, seg = lin & 7;
            *(uint4*)&Bs[row][seg*8] =
                *(const uint4*)(Wt + (size_t)(c0+row)*KCpad + k0 + seg*8);
        }
        __syncthreads();
        #pragma unroll
        for (int ks = 0; ks < 64; ks += 32){
            short8 a0 = *(const short8*)&As[wv*32      + l15][ks + quad*8];
            short8 a1 = *(const short8*)&As[wv*32 + 16 + l15][ks + quad*8];
            short8 b0 = *(const short8*)&Bs[     l15][ks + quad*8];
            short8 b1 = *(const short8*)&Bs[16 + l15][ks + quad*8];
            short8 b2 = *(const short8*)&Bs[32 + l15][ks + quad*8];
            short8 b3 = *(const short8*)&Bs[48 + l15][ks + quad*8];
            acc[0][0] = __builtin_amdgcn_mfma_f32_16x16x32_bf16(a0,b0,acc[0][0],0,0,0);
            acc[0][1] = __builtin_amdgcn_mfma_f32_16x16x32_bf16(a0,b1,acc[0][1],0,0,0);
            acc[0][2] = __builtin_amdgcn_mfma_f32_16x16x32_bf16(a0,b2,acc[0][2],0,0,0);
            acc[0][3] = __builtin_amdgcn_mfma_f32_16x16x32_bf16(a0,b3,acc[0][3],0,0,0);
            acc[1][0] = __builtin_amdgcn_mfma_f32_16x16x32_bf16(a1,b0,acc[1][0],0,0,0);
            acc[1][1] = __builtin_amdgcn_mfma_f32_16x16x32_bf16(a1,b1,acc[1][1],0,0,0);
            acc[1][2] = __builtin_amdgcn_mfma_f32_16x16x32_bf16(a1,b2,acc[1][2],0,0,0);
            acc[1][3] = __builtin_amdgcn_mfma_f32_16x16x32_bf16(a1,b3,acc[1][3],0,0,0);
        }
        __syncthreads();
    }
    #pragma unroll
    for (int i=0;i<2;++i){
        #pragma unroll
        for (int j=0;j<4;++j){
            int c = c0 + j*16 + l15;
            #pragma unroll
            for (int r=0;r<4;++r){
                int gr = r0 + wv*32 + i*16 + quad*4 + r;
                if (gr >= rows) continue;
                float v = acc[i][j][r] + bias[c];
                if (MODE == 0){
                    v = 1.f/(1.f + __expf(-v));
                    zr[(size_t)gr*256 + c] = v;
                } else {
                    float hc   = tanhf(v);
                    float z    = zr[(size_t)gr*256 + c];
                    float hold = hb[(size_t)gr*128 + c];
                    hb[(size_t)gr*128 + c] = z*hold + (1.f - z)*hc;
                }
            }
        }
    }
}

// ---------------------------------------------------------------------------
// Projection: out = h1 @ Wp + bp ; fp32 xdec + fp32 d_out
// ---------------------------------------------------------------------------
__global__ __launch_bounds__(256) void proj(const float* __restrict__ h1,
                                            const float* __restrict__ Wp,
                                            const float* __restrict__ bp,
                                            float* __restrict__ xdec,
                                            float* __restrict__ out, int t){
    int row  = blockIdx.x * 4 + (threadIdx.x >> 6);
    int lane = threadIdx.x & 63;
    float v0 = h1[(size_t)row*128 + lane];
    float v1 = h1[(size_t)row*128 + 64 + lane];
    float w00 = Wp[lane*2+0],      w01 = Wp[lane*2+1];
    float w10 = Wp[(64+lane)*2+0], w11 = Wp[(64+lane)*2+1];
    float a0 = v0*w00 + v1*w10;
    float a1 = v0*w01 + v1*w11;
    #pragma unroll
    for (int off=32; off>0; off>>=1){
        a0 += __shfl_down(a0, off);
        a1 += __shfl_down(a1, off);
    }
    if (lane == 0){
        a0 += bp[0];
        a1 += bp[1];
        xdec[(size_t)row*2+0] = a0;
        xdec[(size_t)row*2+1] = a1;
        int b = row / N_, n = row % N_;
        size_t o = ((size_t)(b*T_ + t)*N_ + n)*2;
        out[o]   = a0;
        out[o+1] = a1;
    }
}

// ---------------------------------------------------------------------------
extern "C" void kernel_launch(void* const* d_in, const int* in_sizes, int n_in,
                              void* d_out, int out_size, void* d_ws, size_t ws_size,
                              hipStream_t stream){
    float* out = (float*)d_out;

    char* pb = (char*)d_ws;
    auto alloc = [&](size_t bytes)->void*{
        void* r = (void*)pb;
        pb += (bytes + 255) & ~(size_t)255;
        return r;
    };

    int* flag = (int*)alloc(16);
    sniff<<<1, 64, 0, stream>>>(d_in[2], flag);

    // fp32 copies of float inputs (skip targets idx 1)
    float* cw[21];
    const int idxs[20] = {0,2,3,4,5,6,7,8,9,10,11,12,13,14,15,16,17,18,19,20};
    for (int ii = 0; ii < 20; ++ii){
        int i = idxs[ii];
        int n = in_sizes[i];
        cw[i] = (float*)alloc((size_t)n*4);
        cvt<<<dim3((n+255)/256), 256, 0, stream>>>(d_in[i], cw[i], n, flag);
    }
    const float* src = cw[0];

    float* msq  = (float*)alloc((size_t)4*N_*N_*4);
    float* h0   = (float*)alloc((size_t)BN*H_*4);
    float* h1   = (float*)alloc((size_t)BN*H_*4);
    float* xdec = (float*)alloc((size_t)BN*DIN*4);
    u16*   asq  = (u16*)alloc((size_t)4*N_*DPITCH*2);

    // pre-transposed bf16 weights: Wt[Nout][KCpad]
    // weight idx: 3,5 (enc0 g/c KC=650), 7,9 (enc1 KC=1280), 11,13 (dec0), 15,17 (dec1)
    const int widx[8]  = {3,5,7,9,11,13,15,17};
    const int wKC[8]   = {650,650,1280,1280,650,650,1280,1280};
    const int wNout[8] = {256,128,256,128,256,128,256,128};
    u16* wt[8];
    for (int i=0;i<8;++i){
        int KCpad = (wKC[i] + 63) & ~63;
        wt[i] = (u16*)alloc((size_t)wNout[i]*KCpad*2);
        wtrans<<<dim3(KCpad/64, wNout[i]/64), 256, 0, stream>>>(cw[widx[i]], wt[i], wKC[i], wNout[i], KCpad);
    }

    // adaptive chunk: F (Bc*N*1280 bf16) + zr (Bc*N*256 f32) + Ft (Bc*256*384 bf16)
    size_t fixed = (size_t)(pb - (char*)d_ws);
    size_t perb  = (size_t)N_*1280*2 + (size_t)N_*256*4 + (size_t)256*DPITCH*2;
    int Bc = 64;
    while (Bc > 1 && fixed + 1024 + (size_t)Bc*perb > ws_size) Bc >>= 1;
    float* zr = (float*)alloc((size_t)Bc*N_*256*4);
    u16*   F  = (u16*)alloc((size_t)Bc*N_*1280*2);
    u16*   Ft = (u16*)alloc((size_t)Bc*256*DPITCH*2);

    {   // supports + squared supports, then bf16-padded copy
        dim3 g((N_+15)/16, (N_+15)/16, 2), b(16,16);
        support_prep<<<g, b, 0, stream>>>(cw[2], msq);
        int tot = 4*N_*DPITCH;
        asq_prep<<<dim3((tot+255)/256), 256, 0, stream>>>(msq, asq);
    }
    hipMemsetAsync(h0, 0, sizeof(float)*(size_t)BN*H_*2, stream);  // h0 and h1

    auto cell = [&](int layer, const float* x, long xbs, float* h,
                    const u16* Wg, const float* bg, const u16* Wc, const float* bc){
        int C     = layer ? 256 : 130;
        int KC    = 5*C;
        int KCpad = (KC + 63) & ~63;
        int Din   = layer ? 128 : 2;
        int ctiles = (C + 63)/64;
        int Cpad   = ctiles*64;
        for (int b0 = 0; b0 < B_; b0 += Bc){
            int rows = Bc*N_;
            int gy   = (rows + 127)/128;
            float* hb = h + (size_t)b0*N_*H_;
            dim3 gd(ctiles, (N_+127)/128, 4*Bc);
            dim3 gt(DPITCH/64, Cpad/64, Bc);
            fill_xh<<<dim3((rows*C+255)/256), 256, 0, stream>>>(F, C, KC, Din, b0, Bc, x, xbs, h);
            ftrans<<<gt, 256, 0, stream>>>(F, Ft, C, KC, Cpad);
            diffuse_mfma<<<gd, 256, 0, stream>>>(F, Ft, asq, C, KC, Cpad);
            gemm_mfma<0><<<dim3(4, gy), 256, 0, stream>>>(F, KC, rows, Wg, KCpad, bg, 256, zr, (float*)nullptr);
            fill_rh<<<dim3((rows*H_+255)/256), 256, 0, stream>>>(F, KC, Din, b0, Bc, zr, h);
            ftrans<<<gt, 256, 0, stream>>>(F, Ft, C, KC, Cpad);
            diffuse_mfma<<<gd, 256, 0, stream>>>(F, Ft, asq, C, KC, Cpad);
            gemm_mfma<1><<<dim3(2, gy), 256, 0, stream>>>(F, KC, rows, Wc, KCpad, bc, 128, zr, hb);
        }
    };

    // ---------------- encoder ----------------
    for (int t = 0; t < T_; ++t){
        cell(0, src + (size_t)t*N_*DIN, (long)T_*N_*DIN, h0, wt[0], cw[4], wt[1], cw[6]);
        cell(1, h0, (long)N_*H_, h1, wt[2], cw[8], wt[3], cw[10]);
    }

    // ---------------- decoder ----------------
    hipMemsetAsync(xdec, 0, sizeof(float)*(size_t)BN*DIN, stream);
    for (int t = 0; t < T_; ++t){
        cell(0, xdec, (long)N_*DIN, h0, wt[4], cw[12], wt[5], cw[14]);
        cell(1, h0, (long)N_*H_, h1, wt[6], cw[16], wt[7], cw[18]);
        proj<<<dim3(BN/4), 256, 0, stream>>>(h1, cw[19], cw[20], xdec, out, t);
    }
}

// Round 7
// 9610.338 us; speedup vs baseline: 4.9290x; 1.0388x over previous
//
#include <hip/hip_runtime.h>
#include <hip/hip_bf16.h>

#define B_  64
#define T_  12
#define N_  325
#define DIN 2
#define H_  128
#define BN  (B_*N_)    // 20800
#define DPITCH 384     // padded node pitch for transposed/support buffers

typedef __hip_bfloat16 bf16;
typedef unsigned short u16;
typedef __attribute__((ext_vector_type(8))) short short8;
typedef __attribute__((ext_vector_type(4))) float f32x4;

__device__ __forceinline__ float b2f(bf16 v){ return __bfloat162float(v); }
__device__ __forceinline__ u16 f2b(float f){
    __hip_bfloat16 h = __float2bfloat16(f);
    return *reinterpret_cast<u16*>(&h);
}

// ---------------------------------------------------------------------------
// Dtype sniffer + one-shot fp32 conversion of all float inputs
// ---------------------------------------------------------------------------
__global__ void sniff(const void* __restrict__ sup, int* __restrict__ flag){
    if (threadIdx.x == 0 && blockIdx.x == 0){
        float sb = 0.f, sf = 0.f;
        for (int n = 0; n < N_; ++n){
            sb += b2f(((const bf16*)sup)[n]);
            sf += ((const float*)sup)[n];
        }
        float db = fabsf(sb - 1.f), df = fabsf(sf - 1.f);
        *flag = (db < df) ? 1 : 0;
    }
}

struct CvtArgs {
    const void* src[20];
    float*      dst[20];
    int         n[20];
};

__global__ void cvt_all(CvtArgs a, const int* __restrict__ flag){
    int ii = blockIdx.y;
    int i  = blockIdx.x*256 + threadIdx.x;
    int n  = a.n[ii];
    if (i >= n) return;
    if (*flag) a.dst[ii][i] = b2f(((const bf16*)a.src[ii])[i]);
    else       a.dst[ii][i] = ((const float*)a.src[ii])[i];
}

// ---------------------------------------------------------------------------
// msq[0]=S0, msq[1]=S0@S0, msq[2]=S1, msq[3]=S1@S1   (fp32)
// ---------------------------------------------------------------------------
__global__ void support_prep(const float* __restrict__ sup, float* __restrict__ msq){
    int s = blockIdx.z;
    int m = blockIdx.y*16 + threadIdx.y;
    int n = blockIdx.x*16 + threadIdx.x;
    __shared__ float As[16][17], Bs[16][17];
    const float* S = sup + (size_t)s*N_*N_;
    float acc = 0.f;
    for (int j0 = 0; j0 < N_; j0 += 16){
        As[threadIdx.y][threadIdx.x] = (m < N_ && j0+threadIdx.x < N_) ? S[m*N_ + j0+threadIdx.x] : 0.f;
        Bs[threadIdx.y][threadIdx.x] = (j0+threadIdx.y < N_ && n < N_) ? S[(j0+threadIdx.y)*N_ + n] : 0.f;
        __syncthreads();
        #pragma unroll
        for (int jj=0; jj<16; ++jj) acc += As[threadIdx.y][jj]*Bs[jj][threadIdx.x];
        __syncthreads();
    }
    if (m < N_ && n < N_){
        msq[(size_t)(2*s  )*N_*N_ + m*N_ + n] = S[m*N_ + n];
        msq[(size_t)(2*s+1)*N_*N_ + m*N_ + n] = acc;
    }
}

// asq[k][m][col] = bf16(msq[k][m][col]) zero-padded to DPITCH cols
__global__ void asq_prep(const float* __restrict__ msq, u16* __restrict__ asq){
    int idx = blockIdx.x*256 + threadIdx.x;
    int total = 4*N_*DPITCH;
    if (idx >= total) return;
    int col = idx % DPITCH;
    int rm  = idx / DPITCH;
    int m   = rm % N_;
    int k   = rm / N_;
    asq[idx] = (col < N_) ? f2b(msq[((size_t)k*N_ + m)*N_ + col]) : 0;
}

// ---------------------------------------------------------------------------
// Weight transpose: W[KC][Nout] fp32 -> Wt[Nout][KCpad] bf16 (k zero-padded)
// ---------------------------------------------------------------------------
__global__ __launch_bounds__(256) void wtrans(const float* __restrict__ W, u16* __restrict__ Wt,
                                              int KC, int Nout, int KCpad){
    int k0 = blockIdx.x*64, c0 = blockIdx.y*64;
    int tid = threadIdx.x;
    __shared__ u16 T[64][72];
    #pragma unroll
    for (int it=0; it<2; ++it){
        int lin = it*256 + tid;
        int kl = lin >> 3, seg = lin & 7;
        int gk = k0 + kl, gc = c0 + seg*8;
        u16 tmp[8];
        #pragma unroll
        for (int e=0;e<8;++e) tmp[e] = (gk < KC) ? f2b(W[(size_t)gk*Nout + gc + e]) : 0;
        *(uint4*)&T[kl][seg*8] = *(const uint4*)tmp;
    }
    __syncthreads();
    #pragma unroll
    for (int it=0; it<2; ++it){
        int lin = it*256 + tid;
        int cl = lin >> 3, seg = lin & 7;
        u16 tmp[8];
        #pragma unroll
        for (int j=0;j<8;++j) tmp[j] = T[seg*8+j][cl];
        *(uint4*)(Wt + (size_t)(c0+cl)*KCpad + k0 + seg*8) = *(const uint4*)tmp;
    }
}

// ---------------------------------------------------------------------------
// fill_t: build F slot0 = [x|h] (bf16, row-major) AND Ft = transpose (c-major,
// node pitch DPITCH, zero-padded). grid (DPITCH/64, Cpad/64, Bc)
// ---------------------------------------------------------------------------
__global__ __launch_bounds__(256) void fill_t(u16* __restrict__ F, u16* __restrict__ Ft,
                                              int C, int KC, int Cpad, int Din, int b0,
                                              const float* __restrict__ x, long xbs,
                                              const float* __restrict__ h){
    int bl = blockIdx.z;
    int bg = b0 + bl;
    int n0 = blockIdx.x*64, c0 = blockIdx.y*64;
    int tid = threadIdx.x;
    __shared__ u16 T[64][72];
    #pragma unroll
    for (int it=0; it<2; ++it){
        int lin = it*256 + tid;
        int nl = lin >> 3, seg = lin & 7;
        int gn = n0 + nl;
        u16 tmp[8];
        #pragma unroll
        for (int e=0;e<8;++e){
            int c = c0 + seg*8 + e;
            float v = 0.f;
            if (gn < N_ && c < C)
                v = (c < Din) ? x[(size_t)bg*xbs + (size_t)gn*Din + c]
                              : h[((size_t)bg*N_ + gn)*H_ + (c - Din)];
            tmp[e] = f2b(v);
        }
        *(uint4*)&T[nl][seg*8] = *(const uint4*)tmp;
        if (gn < N_){
            int cbase = c0 + seg*8;
            u16* dst = F + ((size_t)bl*N_ + gn)*KC + cbase;
            if (cbase + 7 < C){
                *(uint4*)dst = *(const uint4*)tmp;
            } else {
                #pragma unroll
                for (int e=0;e<8;++e) if (cbase + e < C) dst[e] = tmp[e];
            }
        }
    }
    __syncthreads();
    #pragma unroll
    for (int it=0; it<2; ++it){
        int lin = it*256 + tid;
        int cl = lin >> 3, seg = lin & 7;
        u16 tmp[8];
        #pragma unroll
        for (int j=0;j<8;++j) tmp[j] = T[seg*8+j][cl];
        *(uint4*)(Ft + (size_t)bl*Cpad*DPITCH + (size_t)(c0+cl)*DPITCH + n0 + seg*8)
            = *(const uint4*)tmp;
    }
}

// ---------------------------------------------------------------------------
// rh_fill: F[slot0 h-part] = Ft[h-rows] = bf16(r * h)
// ---------------------------------------------------------------------------
__global__ void rh_fill(u16* __restrict__ F, u16* __restrict__ Ft,
                        int KC, int Cpad, int Din, int b0,
                        const float* __restrict__ zr, const float* __restrict__ h){
    int idx = blockIdx.x*256 + threadIdx.x;
    int j   = idx & 127;
    int bnl = idx >> 7;          // grid sized exactly Bc*N_*128/256
    int bl  = bnl / N_;
    int n   = bnl % N_;
    float r  = zr[(size_t)bnl*256 + 128 + j];
    float hv = h[((size_t)b0*N_ + bnl)*128 + j];
    u16 v = f2b(r * hv);
    F[(size_t)bnl*KC + Din + j] = v;
    Ft[((size_t)bl*Cpad + Din + j)*DPITCH + n] = v;
}

// ---------------------------------------------------------------------------
// MFMA diffusion: out cols [coff, coff+64*gridx) of each slot:
//   F[bl, m, (k+1)C + coff + c] = sum_n Sk[m,n] * Ft[bl, coff+c, n]
// Block 128(m) x 64(c), BK=64, 4 waves.
// ---------------------------------------------------------------------------
__global__ __launch_bounds__(256) void diffuse_mfma(u16* __restrict__ F,
                                                    const u16* __restrict__ Ft,
                                                    const u16* __restrict__ asq,
                                                    int C, int KC, int Cpad, int coff){
    int zi = blockIdx.z;
    int k  = zi & 3, bl = zi >> 2;
    const u16* A    = asq + (size_t)k*N_*DPITCH;
    const u16* Bt_g = Ft + (size_t)bl*Cpad*DPITCH + (size_t)coff*DPITCH;
    u16*       Cm   = F + (size_t)bl*N_*KC + (size_t)(k+1)*C + coff;

    int m0 = blockIdx.y * 128;
    int c0 = blockIdx.x * 64;
    int tid = threadIdx.x;
    int wv = tid >> 6, lane = tid & 63, l15 = lane & 15, quad = lane >> 4;

    __shared__ u16 As[128][72];
    __shared__ u16 Bt[64][72];

    f32x4 acc[2][4];
    #pragma unroll
    for (int i=0;i<2;++i)
        #pragma unroll
        for (int j=0;j<4;++j) acc[i][j] = (f32x4){0.f,0.f,0.f,0.f};

    for (int k0 = 0; k0 < N_; k0 += 64){
        #pragma unroll
        for (int it=0; it<4; ++it){
            int lin = it*256 + tid;
            int row = lin >> 3, seg = lin & 7;
            int gm = m0 + row;
            uint4 v = {0u,0u,0u,0u};
            if (gm < N_) v = *(const uint4*)(A + (size_t)gm*DPITCH + k0 + seg*8);
            *(uint4*)&As[row][seg*8] = v;
        }
        #pragma unroll
        for (int it=0; it<2; ++it){
            int lin = it*256 + tid;
            int row = lin >> 3, seg = lin & 7;
            *(uint4*)&Bt[row][seg*8] =
                *(const uint4*)(Bt_g + (size_t)(c0+row)*DPITCH + k0 + seg*8);
        }
        __syncthreads();
        #pragma unroll
        for (int ks = 0; ks < 64; ks += 32){
            short8 a0 = *(const short8*)&As[wv*32      + l15][ks + quad*8];
            short8 a1 = *(const short8*)&As[wv*32 + 16 + l15][ks + quad*8];
            short8 b0 = *(const short8*)&Bt[     l15][ks + quad*8];
            short8 b1 = *(const short8*)&Bt[16 + l15][ks + quad*8];
            short8 b2 = *(const short8*)&Bt[32 + l15][ks + quad*8];
            short8 b3 = *(const short8*)&Bt[48 + l15][ks + quad*8];
            acc[0][0] = __builtin_amdgcn_mfma_f32_16x16x32_bf16(a0,b0,acc[0][0],0,0,0);
            acc[0][1] = __builtin_amdgcn_mfma_f32_16x16x32_bf16(a0,b1,acc[0][1],0,0,0);
            acc[0][2] = __builtin_amdgcn_mfma_f32_16x16x32_bf16(a0,b2,acc[0][2],0,0,0);
            acc[0][3] = __builtin_amdgcn_mfma_f32_16x16x32_bf16(a0,b3,acc[0][3],0,0,0);
            acc[1][0] = __builtin_amdgcn_mfma_f32_16x16x32_bf16(a1,b0,acc[1][0],0,0,0);
            acc[1][1] = __builtin_amdgcn_mfma_f32_16x16x32_bf16(a1,b1,acc[1][1],0,0,0);
            acc[1][2] = __builtin_amdgcn_mfma_f32_16x16x32_bf16(a1,b2,acc[1][2],0,0,0);
            acc[1][3] = __builtin_amdgcn_mfma_f32_16x16x32_bf16(a1,b3,acc[1][3],0,0,0);
        }
        __syncthreads();
    }
    #pragma unroll
    for (int i=0;i<2;++i){
        #pragma unroll
        for (int j=0;j<4;++j){
            int c = c0 + j*16 + l15;      // local col; global slot col = coff + c
            #pragma unroll
            for (int r=0;r<4;++r){
                int m = m0 + wv*32 + i*16 + quad*4 + r;
                if (m < N_ && coff + c < C) Cm[(size_t)m*KC + c] = f2b(acc[i][j][r]);
            }
        }
    }
}

// ---------------------------------------------------------------------------
// MFMA GEMM + fused epilogue: out = F(rows x KC) @ W + bias. B from Wt.
// MODE 0: zr = sigmoid(out) (Nout=256). MODE 1: h = z*h + (1-z)*tanh(out).
// ---------------------------------------------------------------------------
template<int MODE>
__global__ __launch_bounds__(256) void gemm_mfma(const u16* __restrict__ Fb, int KC,
                                                 int rows,
                                                 const u16* __restrict__ Wt, int KCpad,
                                                 const float* __restrict__ bias,
                                                 float* __restrict__ zr,
                                                 float* __restrict__ hb){
    int r0 = blockIdx.y * 128;
    int c0 = blockIdx.x * 64;
    int tid = threadIdx.x;
    int wv = tid >> 6, lane = tid & 63, l15 = lane & 15, quad = lane >> 4;

    __shared__ u16 As[128][72];
    __shared__ u16 Bs[64][72];

    f32x4 acc[2][4];
    #pragma unroll
    for (int i=0;i<2;++i)
        #pragma unroll
        for (int j=0;j<4;++j) acc[i][j] = (f32x4){0.f,0.f,0.f,0.f};

    for (int k0 = 0; k0 < KCpad; k0 += 64){
        #pragma unroll
        for (int it=0; it<4; ++it){
            int lin = it*256 + tid;
            int row = lin >> 3, seg = lin & 7;
            int gr = r0 + row, gk = k0 + seg*8;
            if (gr < rows && gk + 7 < KC){
                *(uint4*)&As[row][seg*8] = *(const uint4*)(Fb + (size_t)gr*KC + gk);
            } else {
                u16 tmp[8];
                #pragma unroll
                for (int e=0;e<8;++e)
                    tmp[e] = (gr < rows && gk+e < KC) ? Fb[(size_t)gr*KC + gk+e] : 0;
                *(uint4*)&As[row][seg*8] = *(const uint4*)tmp;
            }
        }
        #pragma unroll
        for (int it=0; it<2; ++it){
            int lin = it*256 + tid;
            int row = lin >> 3, seg = lin & 7;
            *(uint4*)&Bs[row][seg*8] =
                *(const uint4*)(Wt + (size_t)(c0+row)*KCpad + k0 + seg*8);
        }
        __syncthreads();
        #pragma unroll
        for (int ks = 0; ks < 64; ks += 32){
            short8 a0 = *(const short8*)&As[wv*32      + l15][ks + quad*8];
            short8 a1 = *(const short8*)&As[wv*32 + 16 + l15][ks + quad*8];
            short8 b0 = *(const short8*)&Bs[     l15][ks + quad*8];
            short8 b1 = *(const short8*)&Bs[16 + l15][ks + quad*8];
            short8 b2 = *(const short8*)&Bs[32 + l15][ks + quad*8];
            short8 b3 = *(const short8*)&Bs[48 + l15][ks + quad*8];
            acc[0][0] = __builtin_amdgcn_mfma_f32_16x16x32_bf16(a0,b0,acc[0][0],0,0,0);
            acc[0][1] = __builtin_amdgcn_mfma_f32_16x16x32_bf16(a0,b1,acc[0][1],0,0,0);
            acc[0][2] = __builtin_amdgcn_mfma_f32_16x16x32_bf16(a0,b2,acc[0][2],0,0,0);
            acc[0][3] = __builtin_amdgcn_mfma_f32_16x16x32_bf16(a0,b3,acc[0][3],0,0,0);
            acc[1][0] = __builtin_amdgcn_mfma_f32_16x16x32_bf16(a1,b0,acc[1][0],0,0,0);
            acc[1][1] = __builtin_amdgcn_mfma_f32_16x16x32_bf16(a1,b1,acc[1][1],0,0,0);
            acc[1][2] = __builtin_amdgcn_mfma_f32_16x16x32_bf16(a1,b2,acc[1][2],0,0,0);
            acc[1][3] = __builtin_amdgcn_mfma_f32_16x16x32_bf16(a1,b3,acc[1][3],0,0,0);
        }
        __syncthreads();
    }
    #pragma unroll
    for (int i=0;i<2;++i){
        #pragma unroll
        for (int j=0;j<4;++j){
            int c = c0 + j*16 + l15;
            #pragma unroll
            for (int r=0;r<4;++r){
                int gr = r0 + wv*32 + i*16 + quad*4 + r;
                if (gr >= rows) continue;
                float v = acc[i][j][r] + bias[c];
                if (MODE == 0){
                    v = 1.f/(1.f + __expf(-v));
                    zr[(size_t)gr*256 + c] = v;
                } else {
                    float hc   = tanhf(v);
                    float z    = zr[(size_t)gr*256 + c];
                    float hold = hb[(size_t)gr*128 + c];
                    hb[(size_t)gr*128 + c] = z*hold + (1.f - z)*hc;
                }
            }
        }
    }
}

// ---------------------------------------------------------------------------
// Projection: out = h1 @ Wp + bp ; fp32 xdec + fp32 d_out
// ---------------------------------------------------------------------------
__global__ __launch_bounds__(256) void proj(const float* __restrict__ h1,
                                            const float* __restrict__ Wp,
                                            const float* __restrict__ bp,
                                            float* __restrict__ xdec,
                                            float* __restrict__ out, int t){
    int row  = blockIdx.x * 4 + (threadIdx.x >> 6);
    int lane = threadIdx.x & 63;
    float v0 = h1[(size_t)row*128 + lane];
    float v1 = h1[(size_t)row*128 + 64 + lane];
    float w00 = Wp[lane*2+0],      w01 = Wp[lane*2+1];
    float w10 = Wp[(64+lane)*2+0], w11 = Wp[(64+lane)*2+1];
    float a0 = v0*w00 + v1*w10;
    float a1 = v0*w01 + v1*w11;
    #pragma unroll
    for (int off=32; off>0; off>>=1){
        a0 += __shfl_down(a0, off);
        a1 += __shfl_down(a1, off);
    }
    if (lane == 0){
        a0 += bp[0];
        a1 += bp[1];
        xdec[(size_t)row*2+0] = a0;
        xdec[(size_t)row*2+1] = a1;
        int b = row / N_, n = row % N_;
        size_t o = ((size_t)(b*T_ + t)*N_ + n)*2;
        out[o]   = a0;
        out[o+1] = a1;
    }
}

// ---------------------------------------------------------------------------
extern "C" void kernel_launch(void* const* d_in, const int* in_sizes, int n_in,
                              void* d_out, int out_size, void* d_ws, size_t ws_size,
                              hipStream_t stream){
    float* out = (float*)d_out;

    char* pb = (char*)d_ws;
    auto alloc = [&](size_t bytes)->void*{
        void* r = (void*)pb;
        pb += (bytes + 255) & ~(size_t)255;
        return r;
    };

    int* flag = (int*)alloc(16);
    sniff<<<1, 64, 0, stream>>>(d_in[2], flag);

    // fp32 copies of float inputs (skip targets idx 1) — one fused launch
    float* cw[21];
    const int idxs[20] = {0,2,3,4,5,6,7,8,9,10,11,12,13,14,15,16,17,18,19,20};
    CvtArgs ca;
    int maxn = 0;
    for (int ii = 0; ii < 20; ++ii){
        int i = idxs[ii];
        int n = in_sizes[i];
        cw[i] = (float*)alloc((size_t)n*4);
        ca.src[ii] = d_in[i];
        ca.dst[ii] = cw[i];
        ca.n[ii]   = n;
        if (n > maxn) maxn = n;
    }
    cvt_all<<<dim3((maxn+255)/256, 20), 256, 0, stream>>>(ca, flag);
    const float* src = cw[0];

    float* msq  = (float*)alloc((size_t)4*N_*N_*4);
    float* h0   = (float*)alloc((size_t)BN*H_*4);
    float* h1   = (float*)alloc((size_t)BN*H_*4);
    float* xdec = (float*)alloc((size_t)BN*DIN*4);
    u16*   asq  = (u16*)alloc((size_t)4*N_*DPITCH*2);

    // pre-transposed bf16 weights: Wt[Nout][KCpad]
    const int widx[8]  = {3,5,7,9,11,13,15,17};
    const int wKC[8]   = {650,650,1280,1280,650,650,1280,1280};
    const int wNout[8] = {256,128,256,128,256,128,256,128};
    u16* wt[8];
    for (int i=0;i<8;++i){
        int KCpad = (wKC[i] + 63) & ~63;
        wt[i] = (u16*)alloc((size_t)wNout[i]*KCpad*2);
        wtrans<<<dim3(KCpad/64, wNout[i]/64), 256, 0, stream>>>(cw[widx[i]], wt[i], wKC[i], wNout[i], KCpad);
    }

    // adaptive chunk: F (Bc*N*1280 bf16) + zr (Bc*N*256 f32) + Ft (Bc*256*384 bf16)
    size_t fixed = (size_t)(pb - (char*)d_ws);
    size_t perb  = (size_t)N_*1280*2 + (size_t)N_*256*4 + (size_t)256*DPITCH*2;
    int Bc = 64;
    while (Bc > 1 && fixed + 1024 + (size_t)Bc*perb > ws_size) Bc >>= 1;
    float* zr = (float*)alloc((size_t)Bc*N_*256*4);
    u16*   F  = (u16*)alloc((size_t)Bc*N_*1280*2);
    u16*   Ft = (u16*)alloc((size_t)Bc*256*DPITCH*2);

    {   // supports + squared supports, then bf16-padded copy
        dim3 g((N_+15)/16, (N_+15)/16, 2), b(16,16);
        support_prep<<<g, b, 0, stream>>>(cw[2], msq);
        int tot = 4*N_*DPITCH;
        asq_prep<<<dim3((tot+255)/256), 256, 0, stream>>>(msq, asq);
    }
    hipMemsetAsync(h0, 0, sizeof(float)*(size_t)BN*H_*2, stream);  // h0 and h1

    auto cell = [&](int layer, const float* x, long xbs, float* h,
                    const u16* Wg, const float* bg, const u16* Wc, const float* bc){
        int C      = layer ? 256 : 130;
        int KC     = 5*C;
        int KCpad  = (KC + 63) & ~63;
        int Din    = layer ? 128 : 2;
        int ctiles = (C + 63)/64;     // diffuse1 col tiles (3 | 4)
        int Cpad   = ctiles*64;
        for (int b0 = 0; b0 < B_; b0 += Bc){
            int rows = Bc*N_;
            int gy   = (rows + 127)/128;
            float* hb = h + (size_t)b0*N_*H_;
            // P1: slot0 + transpose
            fill_t<<<dim3(DPITCH/64, Cpad/64, Bc), 256, 0, stream>>>(
                F, Ft, C, KC, Cpad, Din, b0, x, xbs, h);
            // P2: gate diffusion (all C cols)
            diffuse_mfma<<<dim3(ctiles, 3, 4*Bc), 256, 0, stream>>>(F, Ft, asq, C, KC, Cpad, 0);
            // P3: gate GEMM
            gemm_mfma<0><<<dim3(4, gy), 256, 0, stream>>>(F, KC, rows, Wg, KCpad, bg, zr, (float*)nullptr);
            // P4: r*h into slot0 h-part + Ft h-rows
            rh_fill<<<dim3((rows*H_)/256), 256, 0, stream>>>(F, Ft, KC, Cpad, Din, b0, zr, h);
            // P5: candidate diffusion — only the 128 h-cols (x-cols reused from P2)
            diffuse_mfma<<<dim3(2, 3, 4*Bc), 256, 0, stream>>>(F, Ft, asq, C, KC, Cpad, Din);
            // P6: candidate GEMM + GRU update
            gemm_mfma<1><<<dim3(2, gy), 256, 0, stream>>>(F, KC, rows, Wc, KCpad, bc, zr, hb);
        }
    };

    // ---------------- encoder ----------------
    for (int t = 0; t < T_; ++t){
        cell(0, src + (size_t)t*N_*DIN, (long)T_*N_*DIN, h0, wt[0], cw[4], wt[1], cw[6]);
        cell(1, h0, (long)N_*H_, h1, wt[2], cw[8], wt[3], cw[10]);
    }

    // ---------------- decoder ----------------
    hipMemsetAsync(xdec, 0, sizeof(float)*(size_t)BN*DIN, stream);
    for (int t = 0; t < T_; ++t){
        cell(0, xdec, (long)N_*DIN, h0, wt[4], cw[12], wt[5], cw[14]);
        cell(1, h0, (long)N_*H_, h1, wt[6], cw[16], wt[7], cw[18]);
        proj<<<dim3(BN/4), 256, 0, stream>>>(h1, cw[19], cw[20], xdec, out, t);
    }
}

// Round 8
// 7253.350 us; speedup vs baseline: 6.5307x; 1.3250x over previous
//
#include <hip/hip_runtime.h>
#include <hip/hip_bf16.h>

#define B_  64
#define T_  12
#define N_  325
#define DIN 2
#define H_  128
#define BN  (B_*N_)    // 20800
#define DPITCH 384     // padded node pitch (k-extent) for transposed/support buffers
#define AROWS 384      // padded m-rows per support matrix

typedef __hip_bfloat16 bf16;
typedef unsigned short u16;
typedef __attribute__((ext_vector_type(8))) short short8;
typedef __attribute__((ext_vector_type(4))) float f32x4;

__device__ __forceinline__ float b2f(bf16 v){ return __bfloat162float(v); }
__device__ __forceinline__ u16 f2b(float f){
    __hip_bfloat16 h = __float2bfloat16(f);
    return *reinterpret_cast<u16*>(&h);
}

// async global->LDS, 16B per lane; dest = base + lane*16 (wave-uniform base)
__device__ __forceinline__ void gl_lds16(const u16* g, u16* l){
    __builtin_amdgcn_global_load_lds(
        (const __attribute__((address_space(1))) unsigned int*)g,
        (__attribute__((address_space(3))) unsigned int*)l, 16, 0, 0);
}

// ---------------------------------------------------------------------------
// Dtype sniffer + one-shot fp32 conversion of all float inputs
// ---------------------------------------------------------------------------
__global__ void sniff(const void* __restrict__ sup, int* __restrict__ flag){
    if (threadIdx.x == 0 && blockIdx.x == 0){
        float sb = 0.f, sf = 0.f;
        for (int n = 0; n < N_; ++n){
            sb += b2f(((const bf16*)sup)[n]);
            sf += ((const float*)sup)[n];
        }
        float db = fabsf(sb - 1.f), df = fabsf(sf - 1.f);
        *flag = (db < df) ? 1 : 0;
    }
}

struct CvtArgs {
    const void* src[20];
    float*      dst[20];
    int         n[20];
};

__global__ void cvt_all(CvtArgs a, const int* __restrict__ flag){
    int ii = blockIdx.y;
    int i  = blockIdx.x*256 + threadIdx.x;
    int n  = a.n[ii];
    if (i >= n) return;
    if (*flag) a.dst[ii][i] = b2f(((const bf16*)a.src[ii])[i]);
    else       a.dst[ii][i] = ((const float*)a.src[ii])[i];
}

// ---------------------------------------------------------------------------
// msq[0]=S0, msq[1]=S0@S0, msq[2]=S1, msq[3]=S1@S1   (fp32)
// ---------------------------------------------------------------------------
__global__ void support_prep(const float* __restrict__ sup, float* __restrict__ msq){
    int s = blockIdx.z;
    int m = blockIdx.y*16 + threadIdx.y;
    int n = blockIdx.x*16 + threadIdx.x;
    __shared__ float As[16][17], Bs[16][17];
    const float* S = sup + (size_t)s*N_*N_;
    float acc = 0.f;
    for (int j0 = 0; j0 < N_; j0 += 16){
        As[threadIdx.y][threadIdx.x] = (m < N_ && j0+threadIdx.x < N_) ? S[m*N_ + j0+threadIdx.x] : 0.f;
        Bs[threadIdx.y][threadIdx.x] = (j0+threadIdx.y < N_ && n < N_) ? S[(j0+threadIdx.y)*N_ + n] : 0.f;
        __syncthreads();
        #pragma unroll
        for (int jj=0; jj<16; ++jj) acc += As[threadIdx.y][jj]*Bs[jj][threadIdx.x];
        __syncthreads();
    }
    if (m < N_ && n < N_){
        msq[(size_t)(2*s  )*N_*N_ + m*N_ + n] = S[m*N_ + n];
        msq[(size_t)(2*s+1)*N_*N_ + m*N_ + n] = acc;
    }
}

// asq[k][m<384][col<384] = bf16(msq[k][m][col]) zero-padded in rows AND cols
__global__ void asq_prep(const float* __restrict__ msq, u16* __restrict__ asq){
    int idx = blockIdx.x*256 + threadIdx.x;
    int total = 4*AROWS*DPITCH;
    if (idx >= total) return;
    int col = idx % DPITCH;
    int rm  = idx / DPITCH;
    int m   = rm % AROWS;
    int k   = rm / AROWS;
    asq[idx] = (m < N_ && col < N_) ? f2b(msq[((size_t)k*N_ + m)*N_ + col]) : 0;
}

// ---------------------------------------------------------------------------
// Weight transpose: W[KC][Nout] fp32 -> Wt[Nout][KCpad] bf16 (k zero-padded)
// ---------------------------------------------------------------------------
__global__ __launch_bounds__(256) void wtrans(const float* __restrict__ W, u16* __restrict__ Wt,
                                              int KC, int Nout, int KCpad){
    int k0 = blockIdx.x*64, c0 = blockIdx.y*64;
    int tid = threadIdx.x;
    __shared__ u16 T[64][72];
    #pragma unroll
    for (int it=0; it<2; ++it){
        int lin = it*256 + tid;
        int kl = lin >> 3, seg = lin & 7;
        int gk = k0 + kl, gc = c0 + seg*8;
        u16 tmp[8];
        #pragma unroll
        for (int e=0;e<8;++e) tmp[e] = (gk < KC) ? f2b(W[(size_t)gk*Nout + gc + e]) : 0;
        *(uint4*)&T[kl][seg*8] = *(const uint4*)tmp;
    }
    __syncthreads();
    #pragma unroll
    for (int it=0; it<2; ++it){
        int lin = it*256 + tid;
        int cl = lin >> 3, seg = lin & 7;
        u16 tmp[8];
        #pragma unroll
        for (int j=0;j<8;++j) tmp[j] = T[seg*8+j][cl];
        *(uint4*)(Wt + (size_t)(c0+cl)*KCpad + k0 + seg*8) = *(const uint4*)tmp;
    }
}

// ---------------------------------------------------------------------------
// fill_t: build F slot0 = [x|h] (bf16, row-major) AND Ft = transpose (c-major,
// node pitch DPITCH, zero-padded). grid (DPITCH/64, Cpad/64, Bc)
// ---------------------------------------------------------------------------
__global__ __launch_bounds__(256) void fill_t(u16* __restrict__ F, u16* __restrict__ Ft,
                                              int C, int KC, int Cpad, int Din, int b0,
                                              const float* __restrict__ x, long xbs,
                                              const float* __restrict__ h){
    int bl = blockIdx.z;
    int bg = b0 + bl;
    int n0 = blockIdx.x*64, c0 = blockIdx.y*64;
    int tid = threadIdx.x;
    __shared__ u16 T[64][72];
    #pragma unroll
    for (int it=0; it<2; ++it){
        int lin = it*256 + tid;
        int nl = lin >> 3, seg = lin & 7;
        int gn = n0 + nl;
        u16 tmp[8];
        #pragma unroll
        for (int e=0;e<8;++e){
            int c = c0 + seg*8 + e;
            float v = 0.f;
            if (gn < N_ && c < C)
                v = (c < Din) ? x[(size_t)bg*xbs + (size_t)gn*Din + c]
                              : h[((size_t)bg*N_ + gn)*H_ + (c - Din)];
            tmp[e] = f2b(v);
        }
        *(uint4*)&T[nl][seg*8] = *(const uint4*)tmp;
        if (gn < N_){
            int cbase = c0 + seg*8;
            u16* dst = F + ((size_t)bl*N_ + gn)*KC + cbase;
            if (cbase + 7 < C){
                *(uint4*)dst = *(const uint4*)tmp;
            } else {
                #pragma unroll
                for (int e=0;e<8;++e) if (cbase + e < C) dst[e] = tmp[e];
            }
        }
    }
    __syncthreads();
    #pragma unroll
    for (int it=0; it<2; ++it){
        int lin = it*256 + tid;
        int cl = lin >> 3, seg = lin & 7;
        u16 tmp[8];
        #pragma unroll
        for (int j=0;j<8;++j) tmp[j] = T[seg*8+j][cl];
        *(uint4*)(Ft + (size_t)bl*Cpad*DPITCH + (size_t)(c0+cl)*DPITCH + n0 + seg*8)
            = *(const uint4*)tmp;
    }
}

// ---------------------------------------------------------------------------
// rh_fill: F[slot0 h-part] = Ft[h-rows] = bf16(r * h)
// ---------------------------------------------------------------------------
__global__ void rh_fill(u16* __restrict__ F, u16* __restrict__ Ft,
                        int KC, int Cpad, int Din, int b0,
                        const float* __restrict__ zr, const float* __restrict__ h){
    int idx = blockIdx.x*256 + threadIdx.x;
    int j   = idx & 127;
    int bnl = idx >> 7;          // grid sized exactly Bc*N_*128/256
    int bl  = bnl / N_;
    int n   = bnl % N_;
    float r  = zr[(size_t)bnl*256 + 128 + j];
    float hv = h[((size_t)b0*N_ + bnl)*128 + j];
    u16 v = f2b(r * hv);
    F[(size_t)bnl*KC + Din + j] = v;
    Ft[((size_t)bl*Cpad + Din + j)*DPITCH + n] = v;
}

// ---------------------------------------------------------------------------
// MFMA diffusion with async LDS staging + XOR-swizzled layout.
//   F[bl, m, (k+1)C + coff + c] = sum_n Sk[m,n] * Ft[bl, coff+c, n]
// Block 128(m) x 64(c), BK=64, 4 waves.  LDS slot (r,s') holds k-seg s'^(r&7).
// ---------------------------------------------------------------------------
__global__ __launch_bounds__(256) void diffuse_mfma(u16* __restrict__ F,
                                                    const u16* __restrict__ Ft,
                                                    const u16* __restrict__ asq,
                                                    int C, int KC, int Cpad, int coff){
    int zi = blockIdx.z;
    int k  = zi & 3, bl = zi >> 2;
    const u16* A    = asq + (size_t)k*AROWS*DPITCH;
    const u16* Bt_g = Ft + (size_t)bl*Cpad*DPITCH + (size_t)coff*DPITCH;
    u16*       Cm   = F + (size_t)bl*N_*KC + (size_t)(k+1)*C + coff;

    int m0 = blockIdx.y * 128;
    int c0 = blockIdx.x * 64;
    int tid = threadIdx.x;
    int wv = tid >> 6, lane = tid & 63, l15 = lane & 15, quad = lane >> 4;
    int lr = lane >> 3, ls = lane & 7;

    __shared__ u16 As[128*64];
    __shared__ u16 Bs[64*64];

    f32x4 acc[2][4];
    #pragma unroll
    for (int i=0;i<2;++i)
        #pragma unroll
        for (int j=0;j<4;++j) acc[i][j] = (f32x4){0.f,0.f,0.f,0.f};

    for (int k0 = 0; k0 < N_; k0 += 64){
        // A tile: 128 rows x 64k, rows padded (AROWS) so no guard
        #pragma unroll
        for (int j=0;j<4;++j){
            int row = wv*32 + j*8 + lr;
            int seg = ls ^ lr;              // row&7 == lr
            gl_lds16(A + (size_t)(m0+row)*DPITCH + k0 + seg*8, &As[(wv*32 + j*8)*64]);
        }
        // B tile: 64 c-rows x 64k from Ft (padded in k)
        #pragma unroll
        for (int j=0;j<2;++j){
            int row = wv*16 + j*8 + lr;
            int seg = ls ^ lr;
            gl_lds16(Bt_g + (size_t)(c0+row)*DPITCH + k0 + seg*8, &Bs[(wv*16 + j*8)*64]);
        }
        __syncthreads();
        #pragma unroll
        for (int ks = 0; ks < 64; ks += 32){
            int sw = (((ks>>3) + quad) ^ (l15 & 7)) << 3;
            short8 a0 = *(const short8*)&As[(wv*32      + l15)*64 + sw];
            short8 a1 = *(const short8*)&As[(wv*32 + 16 + l15)*64 + sw];
            short8 b0 = *(const short8*)&Bs[(     l15)*64 + sw];
            short8 b1 = *(const short8*)&Bs[(16 + l15)*64 + sw];
            short8 b2 = *(const short8*)&Bs[(32 + l15)*64 + sw];
            short8 b3 = *(const short8*)&Bs[(48 + l15)*64 + sw];
            acc[0][0] = __builtin_amdgcn_mfma_f32_16x16x32_bf16(a0,b0,acc[0][0],0,0,0);
            acc[0][1] = __builtin_amdgcn_mfma_f32_16x16x32_bf16(a0,b1,acc[0][1],0,0,0);
            acc[0][2] = __builtin_amdgcn_mfma_f32_16x16x32_bf16(a0,b2,acc[0][2],0,0,0);
            acc[0][3] = __builtin_amdgcn_mfma_f32_16x16x32_bf16(a0,b3,acc[0][3],0,0,0);
            acc[1][0] = __builtin_amdgcn_mfma_f32_16x16x32_bf16(a1,b0,acc[1][0],0,0,0);
            acc[1][1] = __builtin_amdgcn_mfma_f32_16x16x32_bf16(a1,b1,acc[1][1],0,0,0);
            acc[1][2] = __builtin_amdgcn_mfma_f32_16x16x32_bf16(a1,b2,acc[1][2],0,0,0);
            acc[1][3] = __builtin_amdgcn_mfma_f32_16x16x32_bf16(a1,b3,acc[1][3],0,0,0);
        }
        __syncthreads();
    }
    #pragma unroll
    for (int i=0;i<2;++i){
        #pragma unroll
        for (int j=0;j<4;++j){
            int c = c0 + j*16 + l15;      // local col; global slot col = coff + c
            #pragma unroll
            for (int r=0;r<4;++r){
                int m = m0 + wv*32 + i*16 + quad*4 + r;
                if (m < N_ && coff + c < C) Cm[(size_t)m*KC + c] = f2b(acc[i][j][r]);
            }
        }
    }
}

// ---------------------------------------------------------------------------
// MFMA GEMM + fused epilogue, async LDS staging + swizzle.
// MODE 0: zr = sigmoid(out) (Nout=256). MODE 1: h = z*h + (1-z)*tanh(out).
// A K-tail tile (KC not 64-mult) uses guarded VGPR staging into swizzled slots.
// ---------------------------------------------------------------------------
template<int MODE>
__global__ __launch_bounds__(256) void gemm_mfma(const u16* __restrict__ Fb, int KC,
                                                 int rows,
                                                 const u16* __restrict__ Wt, int KCpad,
                                                 const float* __restrict__ bias,
                                                 float* __restrict__ zr,
                                                 float* __restrict__ hb){
    int r0 = blockIdx.y * 128;
    int c0 = blockIdx.x * 64;
    int tid = threadIdx.x;
    int wv = tid >> 6, lane = tid & 63, l15 = lane & 15, quad = lane >> 4;
    int lr = lane >> 3, ls = lane & 7;

    __shared__ u16 As[128*64];
    __shared__ u16 Bs[64*64];

    f32x4 acc[2][4];
    #pragma unroll
    for (int i=0;i<2;++i)
        #pragma unroll
        for (int j=0;j<4;++j) acc[i][j] = (f32x4){0.f,0.f,0.f,0.f};

    for (int k0 = 0; k0 < KCpad; k0 += 64){
        if (k0 + 64 <= KC){
            // full tile: async DMA (rows beyond `rows` read in-workspace garbage;
            // results discarded by the guarded epilogue)
            #pragma unroll
            for (int j=0;j<4;++j){
                int row = wv*32 + j*8 + lr;
                int seg = ls ^ lr;
                gl_lds16(Fb + (size_t)(r0+row)*KC + k0 + seg*8, &As[(wv*32 + j*8)*64]);
            }
        } else {
            // K tail: guarded VGPR staging into the same swizzled layout
            #pragma unroll
            for (int it=0; it<4; ++it){
                int lin = it*256 + tid;
                int row = lin >> 3, sp = lin & 7;
                int seg = sp ^ (row & 7);
                int gr = r0 + row, gk = k0 + seg*8;
                u16 tmp[8];
                #pragma unroll
                for (int e=0;e<8;++e)
                    tmp[e] = (gk+e < KC) ? Fb[(size_t)gr*KC + gk+e] : (u16)0;
                *(uint4*)&As[row*64 + sp*8] = *(const uint4*)tmp;
            }
        }
        #pragma unroll
        for (int j=0;j<2;++j){
            int row = wv*16 + j*8 + lr;
            int seg = ls ^ lr;
            gl_lds16(Wt + (size_t)(c0+row)*KCpad + k0 + seg*8, &Bs[(wv*16 + j*8)*64]);
        }
        __syncthreads();
        #pragma unroll
        for (int ks = 0; ks < 64; ks += 32){
            int sw = (((ks>>3) + quad) ^ (l15 & 7)) << 3;
            short8 a0 = *(const short8*)&As[(wv*32      + l15)*64 + sw];
            short8 a1 = *(const short8*)&As[(wv*32 + 16 + l15)*64 + sw];
            short8 b0 = *(const short8*)&Bs[(     l15)*64 + sw];
            short8 b1 = *(const short8*)&Bs[(16 + l15)*64 + sw];
            short8 b2 = *(const short8*)&Bs[(32 + l15)*64 + sw];
            short8 b3 = *(const short8*)&Bs[(48 + l15)*64 + sw];
            acc[0][0] = __builtin_amdgcn_mfma_f32_16x16x32_bf16(a0,b0,acc[0][0],0,0,0);
            acc[0][1] = __builtin_amdgcn_mfma_f32_16x16x32_bf16(a0,b1,acc[0][1],0,0,0);
            acc[0][2] = __builtin_amdgcn_mfma_f32_16x16x32_bf16(a0,b2,acc[0][2],0,0,0);
            acc[0][3] = __builtin_amdgcn_mfma_f32_16x16x32_bf16(a0,b3,acc[0][3],0,0,0);
            acc[1][0] = __builtin_amdgcn_mfma_f32_16x16x32_bf16(a1,b0,acc[1][0],0,0,0);
            acc[1][1] = __builtin_amdgcn_mfma_f32_16x16x32_bf16(a1,b1,acc[1][1],0,0,0);
            acc[1][2] = __builtin_amdgcn_mfma_f32_16x16x32_bf16(a1,b2,acc[1][2],0,0,0);
            acc[1][3] = __builtin_amdgcn_mfma_f32_16x16x32_bf16(a1,b3,acc[1][3],0,0,0);
        }
        __syncthreads();
    }
    #pragma unroll
    for (int i=0;i<2;++i){
        #pragma unroll
        for (int j=0;j<4;++j){
            int c = c0 + j*16 + l15;
            #pragma unroll
            for (int r=0;r<4;++r){
                int gr = r0 + wv*32 + i*16 + quad*4 + r;
                if (gr >= rows) continue;
                float v = acc[i][j][r] + bias[c];
                if (MODE == 0){
                    v = 1.f/(1.f + __expf(-v));
                    zr[(size_t)gr*256 + c] = v;
                } else {
                    float hc   = tanhf(v);
                    float z    = zr[(size_t)gr*256 + c];
                    float hold = hb[(size_t)gr*128 + c];
                    hb[(size_t)gr*128 + c] = z*hold + (1.f - z)*hc;
                }
            }
        }
    }
}

// ---------------------------------------------------------------------------
// Projection: out = h1 @ Wp + bp ; fp32 xdec + fp32 d_out
// ---------------------------------------------------------------------------
__global__ __launch_bounds__(256) void proj(const float* __restrict__ h1,
                                            const float* __restrict__ Wp,
                                            const float* __restrict__ bp,
                                            float* __restrict__ xdec,
                                            float* __restrict__ out, int t){
    int row  = blockIdx.x * 4 + (threadIdx.x >> 6);
    int lane = threadIdx.x & 63;
    float v0 = h1[(size_t)row*128 + lane];
    float v1 = h1[(size_t)row*128 + 64 + lane];
    float w00 = Wp[lane*2+0],      w01 = Wp[lane*2+1];
    float w10 = Wp[(64+lane)*2+0], w11 = Wp[(64+lane)*2+1];
    float a0 = v0*w00 + v1*w10;
    float a1 = v0*w01 + v1*w11;
    #pragma unroll
    for (int off=32; off>0; off>>=1){
        a0 += __shfl_down(a0, off);
        a1 += __shfl_down(a1, off);
    }
    if (lane == 0){
        a0 += bp[0];
        a1 += bp[1];
        xdec[(size_t)row*2+0] = a0;
        xdec[(size_t)row*2+1] = a1;
        int b = row / N_, n = row % N_;
        size_t o = ((size_t)(b*T_ + t)*N_ + n)*2;
        out[o]   = a0;
        out[o+1] = a1;
    }
}

// ---------------------------------------------------------------------------
extern "C" void kernel_launch(void* const* d_in, const int* in_sizes, int n_in,
                              void* d_out, int out_size, void* d_ws, size_t ws_size,
                              hipStream_t stream){
    float* out = (float*)d_out;

    char* pb = (char*)d_ws;
    auto alloc = [&](size_t bytes)->void*{
        void* r = (void*)pb;
        pb += (bytes + 255) & ~(size_t)255;
        return r;
    };

    int* flag = (int*)alloc(16);
    sniff<<<1, 64, 0, stream>>>(d_in[2], flag);

    // fp32 copies of float inputs (skip targets idx 1) — one fused launch
    float* cw[21];
    const int idxs[20] = {0,2,3,4,5,6,7,8,9,10,11,12,13,14,15,16,17,18,19,20};
    CvtArgs ca;
    int maxn = 0;
    for (int ii = 0; ii < 20; ++ii){
        int i = idxs[ii];
        int n = in_sizes[i];
        cw[i] = (float*)alloc((size_t)n*4);
        ca.src[ii] = d_in[i];
        ca.dst[ii] = cw[i];
        ca.n[ii]   = n;
        if (n > maxn) maxn = n;
    }
    cvt_all<<<dim3((maxn+255)/256, 20), 256, 0, stream>>>(ca, flag);
    const float* src = cw[0];

    float* msq  = (float*)alloc((size_t)4*N_*N_*4);
    float* h0   = (float*)alloc((size_t)BN*H_*4);
    float* h1   = (float*)alloc((size_t)BN*H_*4);
    float* xdec = (float*)alloc((size_t)BN*DIN*4);
    u16*   asq  = (u16*)alloc((size_t)4*AROWS*DPITCH*2);

    // pre-transposed bf16 weights: Wt[Nout][KCpad]
    const int widx[8]  = {3,5,7,9,11,13,15,17};
    const int wKC[8]   = {650,650,1280,1280,650,650,1280,1280};
    const int wNout[8] = {256,128,256,128,256,128,256,128};
    u16* wt[8];
    for (int i=0;i<8;++i){
        int KCpad = (wKC[i] + 63) & ~63;
        wt[i] = (u16*)alloc((size_t)wNout[i]*KCpad*2);
        wtrans<<<dim3(KCpad/64, wNout[i]/64), 256, 0, stream>>>(cw[widx[i]], wt[i], wKC[i], wNout[i], KCpad);
    }

    // adaptive chunk: F + zr + Ft + slack
    size_t fixed = (size_t)(pb - (char*)d_ws);
    size_t perb  = (size_t)N_*1280*2 + (size_t)N_*256*4 + (size_t)256*DPITCH*2;
    int Bc = 64;
    while (Bc > 1 && fixed + (1<<20) + (size_t)Bc*perb > ws_size) Bc >>= 1;
    float* zr = (float*)alloc((size_t)Bc*N_*256*4);
    u16*   F  = (u16*)alloc((size_t)Bc*N_*1280*2);
    u16*   Ft = (u16*)alloc((size_t)Bc*256*DPITCH*2);
    alloc(1<<19);   // slack: OOB-row DMA reads stay inside the workspace

    {   // supports + squared supports, then bf16 row/col-padded copy
        dim3 g((N_+15)/16, (N_+15)/16, 2), b(16,16);
        support_prep<<<g, b, 0, stream>>>(cw[2], msq);
        int tot = 4*AROWS*DPITCH;
        asq_prep<<<dim3((tot+255)/256), 256, 0, stream>>>(msq, asq);
    }
    hipMemsetAsync(h0, 0, sizeof(float)*(size_t)BN*H_*2, stream);  // h0 and h1

    auto cell = [&](int layer, const float* x, long xbs, float* h,
                    const u16* Wg, const float* bg, const u16* Wc, const float* bc){
        int C      = layer ? 256 : 130;
        int KC     = 5*C;
        int KCpad  = (KC + 63) & ~63;
        int Din    = layer ? 128 : 2;
        int ctiles = (C + 63)/64;     // diffuse1 col tiles (3 | 4)
        int Cpad   = ctiles*64;
        for (int b0 = 0; b0 < B_; b0 += Bc){
            int rows = Bc*N_;
            int gy   = (rows + 127)/128;
            float* hb = h + (size_t)b0*N_*H_;
            // P1: slot0 + transpose
            fill_t<<<dim3(DPITCH/64, Cpad/64, Bc), 256, 0, stream>>>(
                F, Ft, C, KC, Cpad, Din, b0, x, xbs, h);
            // P2: gate diffusion (all C cols)
            diffuse_mfma<<<dim3(ctiles, 3, 4*Bc), 256, 0, stream>>>(F, Ft, asq, C, KC, Cpad, 0);
            // P3: gate GEMM
            gemm_mfma<0><<<dim3(4, gy), 256, 0, stream>>>(F, KC, rows, Wg, KCpad, bg, zr, (float*)nullptr);
            // P4: r*h into slot0 h-part + Ft h-rows
            rh_fill<<<dim3((rows*H_)/256), 256, 0, stream>>>(F, Ft, KC, Cpad, Din, b0, zr, h);
            // P5: candidate diffusion — only the 128 h-cols (x-cols reused from P2)
            diffuse_mfma<<<dim3(2, 3, 4*Bc), 256, 0, stream>>>(F, Ft, asq, C, KC, Cpad, Din);
            // P6: candidate GEMM + GRU update
            gemm_mfma<1><<<dim3(2, gy), 256, 0, stream>>>(F, KC, rows, Wc, KCpad, bc, zr, hb);
        }
    };

    // ---------------- encoder ----------------
    for (int t = 0; t < T_; ++t){
        cell(0, src + (size_t)t*N_*DIN, (long)T_*N_*DIN, h0, wt[0], cw[4], wt[1], cw[6]);
        cell(1, h0, (long)N_*H_, h1, wt[2], cw[8], wt[3], cw[10]);
    }

    // ---------------- decoder ----------------
    hipMemsetAsync(xdec, 0, sizeof(float)*(size_t)BN*DIN, stream);
    for (int t = 0; t < T_; ++t){
        cell(0, xdec, (long)N_*DIN, h0, wt[4], cw[12], wt[5], cw[14]);
        cell(1, h0, (long)N_*H_, h1, wt[6], cw[16], wt[7], cw[18]);
        proj<<<dim3(BN/4), 256, 0, stream>>>(h1, cw[19], cw[20], xdec, out, t);
    }
}